// Round 21
// baseline (3323.519 us; speedup 1.0000x reference)
//
#include <hip/hip_runtime.h>
#include <hip/hip_bf16.h>

// ---------------- problem constants ----------------
#define PB 64      // batch
#define PN 512     // set size
#define PFEA 102
#define PE 10
#define PDD 256    // d
#define PH 4
#define PDBIG 1024 // D = d*H
#define PL 3
#define PNDIST 100

typedef __attribute__((ext_vector_type(8))) short s8b;   // 8 bf16 (4 VGPRs)
typedef __attribute__((ext_vector_type(4))) float f4;    // 4 fp32 acc

typedef __attribute__((address_space(1))) const void gvoid_t;
typedef __attribute__((address_space(3))) void lvoid_t;
#define GLDS16(g, s) __builtin_amdgcn_global_load_lds((gvoid_t*)(g), (lvoid_t*)(s), 16, 0, 0)

union bfu { __hip_bfloat16 b; unsigned short u; };

__device__ __forceinline__ float b2f(unsigned short u) {
    return __uint_as_float((unsigned int)u << 16);
}
__device__ __forceinline__ unsigned short f2bu(float v) {
    bfu c; c.b = __float2bfloat16(v); return c.u;
}
__device__ __forceinline__ void split_bf16(float v, __hip_bfloat16& hi, __hip_bfloat16& lo) {
    hi = __float2bfloat16(v);
    lo = __float2bfloat16(v - __bfloat162float(hi));
}
__device__ __forceinline__ void split_u(float v, unsigned short& hu, unsigned short& lu) {
    __hip_bfloat16 h, l; split_bf16(v, h, l);
    bfu c; c.b = h; hu = c.u; c.b = l; lu = c.u;
}

// ---------------- reduction helpers ----------------
__device__ __forceinline__ float block_sum1(float v, float* red, int tid) {
    #pragma unroll
    for (int off = 32; off >= 1; off >>= 1) v += __shfl_xor(v, off);
    __syncthreads();
    if ((tid & 63) == 0) red[tid >> 6] = v;
    __syncthreads();
    return red[0] + red[1] + red[2] + red[3];
}

template<int NR, bool MAXOP>
__device__ __forceinline__ void block_redN(float* v, float* red, int tid) {
    #pragma unroll
    for (int off = 32; off >= 1; off >>= 1) {
        #pragma unroll
        for (int r = 0; r < NR; ++r) {
            float o = __shfl_xor(v[r], off);
            v[r] = MAXOP ? fmaxf(v[r], o) : (v[r] + o);
        }
    }
    __syncthreads();
    if ((tid & 63) == 0) {
        #pragma unroll
        for (int r = 0; r < NR; ++r) red[(tid >> 6) * NR + r] = v[r];
    }
    __syncthreads();
    #pragma unroll
    for (int r = 0; r < NR; ++r) {
        float a = red[r], b = red[NR + r], c = red[2 * NR + r], d = red[3 * NR + r];
        v[r] = MAXOP ? fmaxf(fmaxf(a, b), fmaxf(c, d)) : ((a + b) + (c + d));
    }
    __syncthreads();
}

// ---------------- precompute kernels ----------------
__global__ __launch_bounds__(256) void pst_atomproj(
    const float* __restrict__ atom_fea, const float* __restrict__ comp_W,
    float* __restrict__ atomP)
{
    int a = blockIdx.x, tid = threadIdx.x;
    __shared__ float af[92];
    if (tid < 92) af[tid] = atom_fea[a * 92 + tid];
    __syncthreads();
    float s = 0.0f;
    #pragma unroll 4
    for (int k = 0; k < 92; ++k) s = fmaf(af[k], comp_W[k * PDD + tid], s);
    atomP[a * PDD + tid] = s;
}

__global__ __launch_bounds__(256) void pst_embW_reduce(
    const float* __restrict__ emb_W, float* __restrict__ S0, float* __restrict__ S1)
{
    int f = blockIdx.x, tid = threadIdx.x;
    float s0 = 0.0f, s1 = 0.0f;
    #pragma unroll
    for (int t = 0; t < PE; ++t) {
        float w = emb_W[(f * PE + t) * PDD + tid];
        float tf = (float)t / (float)PE;
        s0 += w;
        s1 = fmaf(2.0f * tf, w, s1);
    }
    S0[f * PDD + tid] = s0;
    S1[f * PDD + tid] = s1;
}

__global__ __launch_bounds__(256) void pst_embW_const(
    const float* __restrict__ emb_W, const float* __restrict__ comp_b,
    const float* __restrict__ emb_b, float* __restrict__ Cv)
{
    int tid = threadIdx.x;
    float s = comp_b[tid] + emb_b[tid];
    for (int m = 0; m < PNDIST * PE; ++m) {
        float tf = (float)(m % PE) / (float)PE;
        s = fmaf(tf * tf, emb_W[m * PDD + tid], s);
    }
    Cv[tid] = s;
}

__global__ __launch_bounds__(256) void pst_wext(
    const float* __restrict__ features, float* __restrict__ wvec)
{
    long i = (long)blockIdx.x * 256 + threadIdx.x;
    wvec[i] = features[i * PFEA];
}

// ---------------- embed: 16 rows/block, f-loop unrolled x4 ----------------
__global__ __launch_bounds__(256) void pst_embed16(
    const float* __restrict__ features, const float* __restrict__ atomP,
    const float* __restrict__ S0, const float* __restrict__ S1,
    const float* __restrict__ Cv, const float* __restrict__ ln_g,
    const float* __restrict__ ln_b, unsigned short* __restrict__ xpk)
{
    int r0 = blockIdx.x * 16, tid = threadIdx.x;
    __shared__ float uv[16][PNDIST];
    __shared__ int idxs[16];
    __shared__ float red[64];
    for (int m = tid; m < 16 * PNDIST; m += 256) {
        int r = m / PNDIST, f = m - r * PNDIST;
        uv[r][f] = 1.0f - features[(long)(r0 + r) * PFEA + 1 + f];
    }
    if (tid < 16) idxs[tid] = (int)features[(long)(r0 + tid) * PFEA + PFEA - 1];
    __syncthreads();

    float acc[16];
    float cv = Cv[tid];
    #pragma unroll
    for (int r = 0; r < 16; ++r) acc[r] = cv + atomP[idxs[r] * PDD + tid];
    for (int f = 0; f < PNDIST; f += 4) {
        float s0v[4], s1v[4];
        #pragma unroll
        for (int u = 0; u < 4; ++u) {
            s0v[u] = S0[(f + u) * PDD + tid];
            s1v[u] = S1[(f + u) * PDD + tid];
        }
        #pragma unroll
        for (int u = 0; u < 4; ++u) {
            #pragma unroll
            for (int r = 0; r < 16; ++r) {
                float uu = uv[r][f + u];
                acc[r] = fmaf(uu, fmaf(uu, s0v[u], s1v[u]), acc[r]);
            }
        }
    }
    float mean[16];
    #pragma unroll
    for (int r = 0; r < 16; ++r) mean[r] = acc[r];
    block_redN<16, false>(mean, red, tid);
    float var[16], dv[16];
    #pragma unroll
    for (int r = 0; r < 16; ++r) { mean[r] *= (1.0f / PDD); dv[r] = acc[r] - mean[r]; var[r] = dv[r] * dv[r]; }
    block_redN<16, false>(var, red, tid);
    #pragma unroll
    for (int r = 0; r < 16; ++r) {
        float y = dv[r] * rsqrtf(var[r] * (1.0f / PDD) + 1e-5f) * ln_g[tid] + ln_b[tid];
        long row = (long)(r0 + r);
        unsigned short hu, lu; split_u(y, hu, lu);
        xpk[row * 512 + tid] = hu;
        xpk[row * 512 + 256 + tid] = lu;
    }
}

// ---------------- 128-tile bf16 MFMA GEMM (BK=64, XOR-swizzled LDS) ----------
// VAR 0: split x split, 3-pass. VAR 1: single x single, 1-pass.
// VAR 3: split x split, 2-pass (Ah Bh + Al Bh) — trunk precision.
// MODE 0: C f32. MODE 4: P split row-pack. MODE 5: P single pack.
template<int MODE, int VAR>
__global__ __launch_bounds__(256) void pst_gemm_bf16(
    const __hip_bfloat16* __restrict__ Ap, const __hip_bfloat16* __restrict__ Bp,
    const float* __restrict__ bias, float* __restrict__ C,
    __hip_bfloat16* __restrict__ P,
    int K, int Nw, long strideA, long strideB, long strideC)
{
    const int lda = (VAR == 1) ? K : 2 * K;
    const int ldb = (VAR == 1) ? K : 2 * K;
    int bz = blockIdx.z;
    Ap += (long)bz * strideA; Bp += (long)bz * strideB;
    if (MODE == 0) C += (long)bz * strideC;
    else P += (long)bz * strideC;

    // T1v2: 2D-rectangular XCD swizzle
    int gx = gridDim.x, gy = gridDim.y;
    int lin = blockIdx.y * gx + blockIdx.x;
    int m0, n0;
    if (((gy & 3) == 0) && ((gx & 1) == 0)) {
        int rm = gy >> 2, rn = gx >> 1;
        int xcd = lin & 7, t = lin >> 3;
        int lm = t % rm, ln = t / rm;
        m0 = ((xcd >> 1) * rm + lm) * 128;
        n0 = ((xcd & 1) * rn + ln) * 128;
    } else {
        m0 = blockIdx.y * 128; n0 = blockIdx.x * 128;
    }

    __shared__ __hip_bfloat16 As[128 * 64];
    __shared__ __hip_bfloat16 Bs[128 * 64];

    int tid = threadIdx.x;
    int w = tid >> 6, l = tid & 63;
    int lr = l & 15, kb = l >> 4;
    int wm = (w >> 1) * 64, wn = (w & 1) * 64;
    int srow = tid >> 3;
    int sg = tid & 7;

    f4 acc[4][4] = {};

    const int K3 = (VAR == 0) ? 3 * K : ((VAR == 3) ? 2 * K : K);
    for (int k0 = 0; k0 < K3; k0 += 64) {
        int kA, kB;
        if (VAR == 0) { kA = (k0 < 2 * K) ? k0 : k0 - 2 * K; kB = (k0 < K) ? k0 : k0 - K; }
        else if (VAR == 3) { kA = k0; kB = (k0 < K) ? k0 : k0 - K; }
        else { kA = k0; kB = k0; }
        #pragma unroll
        for (int s = 0; s < 4; ++s) {
            int r = s * 32 + srow;
            int gsrc = sg ^ (r & 7);
            const __hip_bfloat16* ga = Ap + (long)(m0 + r) * lda + kA + gsrc * 8;
            const __hip_bfloat16* gb = Bp + (long)(n0 + r) * ldb + kB + gsrc * 8;
            GLDS16(ga, As + s * 2048 + w * 512);
            GLDS16(gb, Bs + s * 2048 + w * 512);
        }
        __syncthreads();

        #pragma unroll
        for (int kh = 0; kh < 2; ++kh) {
            s8b af[4], bf[4];
            #pragma unroll
            for (int f = 0; f < 4; ++f) {
                int ra = wm + f * 16 + lr;
                int rb = wn + f * 16 + lr;
                int gr = kh * 4 + kb;
                af[f] = *(const s8b*)(As + ra * 64 + ((gr ^ (ra & 7)) * 8));
                bf[f] = *(const s8b*)(Bs + rb * 64 + ((gr ^ (rb & 7)) * 8));
            }
            #pragma unroll
            for (int i = 0; i < 4; ++i)
                #pragma unroll
                for (int j = 0; j < 4; ++j)
                    acc[i][j] = __builtin_amdgcn_mfma_f32_16x16x32_bf16(af[i], bf[j], acc[i][j], 0, 0, 0);
        }
        __syncthreads();
    }

    // C/D layout: col=lane&15, row=(lane>>4)*4+reg [verified m89/m91]
    #pragma unroll
    for (int i = 0; i < 4; ++i) {
        #pragma unroll
        for (int j = 0; j < 4; ++j) {
            int nbase = n0 + wn + j * 16 + lr;
            int mbase = m0 + wm + i * 16 + kb * 4;
            #pragma unroll
            for (int r = 0; r < 4; ++r) {
                int m = mbase + r;
                int n = nbase;
                float val = acc[i][j][r] + (bias ? bias[n] : 0.0f);
                if (MODE == 0) {
                    C[(long)m * Nw + n] = val;
                } else if (MODE == 4) {
                    __hip_bfloat16 hi, lo; split_bf16(val, hi, lo);
                    long b = (long)m * (2 * Nw) + n;
                    P[b] = hi; P[b + Nw] = lo;
                } else { // MODE 5: single pack
                    P[(long)m * Nw + n] = __float2bfloat16(val);
                }
            }
        }
    }
}

// ---------------- 256-tile 8-wave qkv GEMM (R20: BK=32, LDS 64KB, 2 blocks/CU) ----
// 1-pass e_hi @ W (A split pack, hi half read: lda=2K; B single pack: ldb=K).
// q,k -> single per-head packs [bb*4+h][512][256]; v -> single transposed pack
// [bb][vcol][512] with 8B vectorized writes.
__global__ __launch_bounds__(512) void pst_gemm_qkv256(
    const __hip_bfloat16* __restrict__ Ap, const __hip_bfloat16* __restrict__ Bp,
    const float* __restrict__ bias,
    __hip_bfloat16* __restrict__ Pq, __hip_bfloat16* __restrict__ Pk,
    __hip_bfloat16* __restrict__ Pv, int K)
{
    extern __shared__ __hip_bfloat16 lds[];
    __hip_bfloat16* Asd = lds;              // 2 x 8192 elems (256x32 per buf)
    __hip_bfloat16* Bsd = lds + 16384;      // 2 x 8192 elems

    const int lda = 2 * K;   // A is split [hi|lo]; we read hi half only
    const int ldb = K;       // B is single pack

    int gx = gridDim.x, gy = gridDim.y;
    int lin = blockIdx.y * gx + blockIdx.x;
    int m0, n0;
    if (((gy & 3) == 0) && ((gx & 1) == 0)) {
        int rm = gy >> 2, rn = gx >> 1;
        int xcd = lin & 7, t = lin >> 3;
        int lm = t % rm, ln = t / rm;
        m0 = ((xcd >> 1) * rm + lm) * 256;
        n0 = ((xcd & 1) * rn + ln) * 256;
    } else {
        m0 = blockIdx.y * 256; n0 = blockIdx.x * 256;
    }

    int tid = threadIdx.x;
    int w = tid >> 6, l = tid & 63;
    int lr = l & 15, kb = l >> 4;           // kb in 0..3 -> k granule of 8
    int wm = (w >> 2) * 128;
    int wn = (w & 3) * 64;
    int rs = tid >> 2;                      // staging row within 128-chunk
    int g4 = tid & 3;                       // staging granule (4 per 32-col row)

    f4 acc[8][4] = {};

    const int nt = K / 32;

    auto stage = [&](int tIdx, int buf) {
        int k0 = tIdx * 32;
        #pragma unroll
        for (int i = 0; i < 2; ++i) {
            int r = i * 128 + rs;
            int gs = g4 ^ (r & 3);          // pre-swizzled SOURCE granule
            GLDS16(Ap + (long)(m0 + r) * lda + k0 + gs * 8,
                   Asd + buf * 8192 + i * 4096 + w * 512);
            GLDS16(Bp + (long)(n0 + r) * ldb + k0 + gs * 8,
                   Bsd + buf * 8192 + i * 4096 + w * 512);
        }
    };

    stage(0, 0);
    __syncthreads();

    for (int t = 0; t < nt; ++t) {
        int cur = t & 1;
        if (t + 1 < nt) stage(t + 1, cur ^ 1);

        s8b bfr[4];
        #pragma unroll
        for (int fc = 0; fc < 4; ++fc) {
            int rb = wn + fc * 16 + lr;
            bfr[fc] = *(const s8b*)(Bsd + cur * 8192 + rb * 32 +
                                    (((kb) ^ (rb & 3)) * 8));
        }
        #pragma unroll
        for (int q = 0; q < 4; ++q) {
            s8b afr[2];
            #pragma unroll
            for (int d = 0; d < 2; ++d) {
                int ra = wm + (q * 2 + d) * 16 + lr;
                afr[d] = *(const s8b*)(Asd + cur * 8192 + ra * 32 +
                                       (((kb) ^ (ra & 3)) * 8));
            }
            __builtin_amdgcn_s_setprio(1);
            #pragma unroll
            for (int d = 0; d < 2; ++d)
                #pragma unroll
                for (int fc = 0; fc < 4; ++fc)
                    acc[q * 2 + d][fc] = __builtin_amdgcn_mfma_f32_16x16x32_bf16(
                        afr[d], bfr[fc], acc[q * 2 + d][fc], 0, 0, 0);
            __builtin_amdgcn_s_setprio(0);
        }
        __syncthreads();
    }

    // epilogue: q,k single per-head packs; v single transposed pack (8B writes)
    #pragma unroll
    for (int i = 0; i < 8; ++i) {
        #pragma unroll
        for (int j = 0; j < 4; ++j) {
            int nbase = n0 + wn + j * 16 + lr;
            int mbase = m0 + wm + i * 16 + kb * 4;
            if ((nbase >> 10) == 2) {
                int np = nbase & 1023;
                unsigned short hu[4];
                #pragma unroll
                for (int r = 0; r < 4; ++r)
                    hu[r] = f2bu(acc[i][j][r] + bias[nbase]);
                int bb = mbase >> 9, rr0 = mbase & 511;
                unsigned short* pv = (unsigned short*)Pv + ((long)bb * PDBIG + np) * 512;
                *(ushort4*)(pv + rr0) = make_ushort4(hu[0], hu[1], hu[2], hu[3]);
            } else {
                #pragma unroll
                for (int r = 0; r < 4; ++r) {
                    int m = mbase + r;
                    int n = nbase;
                    float val = acc[i][j][r] + bias[n];
                    int bb = m >> 9, rr = m & 511;
                    int reg2 = n >> 10, np = n & 1023;
                    __hip_bfloat16* dst = (reg2 == 0) ? Pq : Pk;
                    int h = np >> 8, kk = np & 255;
                    dst[(((long)bb * 4 + h) * 512 + rr) * 256 + kk] = __float2bfloat16(val);
                }
            }
        }
    }
}

// ---------------- pack helpers ----------------
__global__ __launch_bounds__(256) void pst_pack_rows(
    const float* __restrict__ src, __hip_bfloat16* __restrict__ dst, int kshift)
{
    long i = (long)blockIdx.x * 256 + threadIdx.x;
    int K = 1 << kshift;
    long m = i >> kshift; int k = (int)(i & (K - 1));
    float v = src[i];
    __hip_bfloat16 hi, lo; split_bf16(v, hi, lo);
    long b = (m << (kshift + 1)) + k;
    dst[b] = hi; dst[b + K] = lo;
}

__global__ __launch_bounds__(256) void pst_packT_wL(
    const float* __restrict__ W, __hip_bfloat16* __restrict__ dst,
    int K, int N, long sSrc, long sDst)
{
    int lyr = blockIdx.y;
    long i = (long)blockIdx.x * 256 + threadIdx.x;
    int k = (int)(i / N), n = (int)(i - (long)k * N);
    float v = W[lyr * sSrc + i];
    __hip_bfloat16 hi, lo; split_bf16(v, hi, lo);
    long b = lyr * sDst + (long)n * (2 * K) + k;
    dst[b] = hi; dst[b + K] = lo;
}

// transpose pack, hi-only (single): W [L][K][N] f32 -> dst [L][N][K] bf16
__global__ __launch_bounds__(256) void pst_packT_single(
    const float* __restrict__ W, __hip_bfloat16* __restrict__ dst,
    int K, int N, long sSrc, long sDst)
{
    int lyr = blockIdx.y;
    long i = (long)blockIdx.x * 256 + threadIdx.x;
    int k = (int)(i / N), n = (int)(i - (long)k * N);
    float v = W[lyr * sSrc + i];
    dst[lyr * sDst + (long)n * K + k] = __float2bfloat16(v);
}

__global__ __launch_bounds__(256) void pst_bias_comb(
    const float* __restrict__ b1, const float* __restrict__ W2,
    const float* __restrict__ b2, float* __restrict__ out, int outOff)
{
    int lyr = blockIdx.y;
    int n = blockIdx.x * 256 + threadIdx.x;
    const float* b1l = b1 + (size_t)lyr * PDBIG;
    const float* W2l = W2 + (size_t)lyr * PDBIG * PDBIG;
    float s = b2[(size_t)lyr * PDBIG + n];
    for (int k2 = 0; k2 < PDBIG; ++k2)
        s = fmaf(b1l[k2], W2l[(long)k2 * PDBIG + n], s);
    out[(size_t)lyr * 3072 + outOff + n] = s;
}

__global__ __launch_bounds__(256) void pst_bias_oe(
    const float* __restrict__ bout, const float* __restrict__ Wemb,
    const float* __restrict__ bemb, float* __restrict__ boe)
{
    int lyr = blockIdx.y;
    int n = blockIdx.x * 256 + threadIdx.x;
    const float* b1 = bout + (size_t)lyr * PDD;
    const float* W  = Wemb + (size_t)(lyr + 1) * PDD * PDBIG;
    float s = bemb[(size_t)(lyr + 1) * PDBIG + n];
    #pragma unroll 4
    for (int k = 0; k < PDD; ++k)
        s = fmaf(b1[k], W[(long)k * PDBIG + n], s);
    boe[(size_t)lyr * PDBIG + n] = s;
}

__global__ __launch_bounds__(256) void pst_vbias(
    const float* __restrict__ src, float* __restrict__ out)
{
    int lyr = blockIdx.y;
    int i = blockIdx.x * 256 + threadIdx.x;
    out[(size_t)lyr * 3072 + 2048 + i] = src[(size_t)lyr * PDBIG + i];
}

// ---------------- attention softmax (no mask; single S/A) ----------
__global__ __launch_bounds__(256) void pst_attnSM(
    const unsigned short* __restrict__ Sp, const float* __restrict__ wvec,
    __hip_bfloat16* __restrict__ Apack, int bGlobBase)
{
    int blk = blockIdx.x;
    int bLoc = blk >> 6;
    int q0 = (blk & 63) << 3;
    int tid = threadIdx.x;
    int w = tid >> 6, lane = tid & 63;
    int r0 = q0 + w * 2;
    int bGlob = bGlobBase + bLoc;

    float wcol[8];
    #pragma unroll
    for (int j = 0; j < 8; ++j)
        wcol[j] = wvec[(long)bGlob * PN + lane + 64 * j];
    const float scale = 0.0625f;
    float pacc[2][8] = {};

    for (int h = 0; h < PH; ++h) {
        const unsigned short* Sh = Sp + (((long)(bLoc * 4 + h)) * 512 + r0) * 512;
        #pragma unroll
        for (int rr = 0; rr < 2; ++rr) {
            float s[8]; float mx = -1e30f;
            #pragma unroll
            for (int j = 0; j < 8; ++j) {
                float a = b2f(Sh[(long)rr * 512 + lane + 64 * j]) * scale;
                s[j] = a; mx = fmaxf(mx, a);
            }
            #pragma unroll
            for (int off = 32; off >= 1; off >>= 1) mx = fmaxf(mx, __shfl_xor(mx, off));
            float sum = 0.0f;
            #pragma unroll
            for (int j = 0; j < 8; ++j) { s[j] = __expf(s[j] - mx); sum += s[j]; }
            #pragma unroll
            for (int off = 32; off >= 1; off >>= 1) sum += __shfl_xor(sum, off);
            float inv = 1.0f / sum;
            #pragma unroll
            for (int j = 0; j < 8; ++j) pacc[rr][j] = fmaf(s[j], inv, pacc[rr][j]);
        }
    }
    #pragma unroll
    for (int rr = 0; rr < 2; ++rr) {
        float asum = 0.0f;
        #pragma unroll
        for (int j = 0; j < 8; ++j) { pacc[rr][j] *= wcol[j]; asum += pacc[rr][j]; }
        #pragma unroll
        for (int off = 32; off >= 1; off >>= 1) asum += __shfl_xor(asum, off);
        float inv = 1.0f / asum;
        long rowb = ((long)bLoc * PN + r0 + rr) * 512;
        #pragma unroll
        for (int j = 0; j < 8; ++j) {
            int c = lane + 64 * j;
            Apack[rowb + c] = __float2bfloat16(pacc[rr][j] * inv);
        }
    }
}

// ---------------- spln ----------------
__global__ __launch_bounds__(256) void pst_spln(
    const float* __restrict__ att, __hip_bfloat16* __restrict__ ep,
    const float* __restrict__ g, const float* __restrict__ bb)
{
    int r = blockIdx.x, tid = threadIdx.x;
    __shared__ float red[4];
    int i0 = tid * 4;
    unsigned short* epu = (unsigned short*)ep + (long)r * 2048;
    ushort4 h4 = *(const ushort4*)(epu + i0);
    ushort4 l4 = *(const ushort4*)(epu + 1024 + i0);
    float4 a4 = *(const float4*)(att + (long)r * 1024 + i0);
    float v[4];
    {
        float av[4] = {a4.x, a4.y, a4.z, a4.w};
        unsigned short hv[4] = {h4.x, h4.y, h4.z, h4.w};
        unsigned short lv[4] = {l4.x, l4.y, l4.z, l4.w};
        #pragma unroll
        for (int j = 0; j < 4; ++j) {
            float a = av[j];
            float sp = (a > 20.0f) ? a : log1pf(expf(a));
            v[j] = b2f(hv[j]) + b2f(lv[j]) + sp;
        }
    }
    float s = v[0] + v[1] + v[2] + v[3];
    float mean = block_sum1(s, red, tid) * (1.0f / PDBIG);
    float vs = 0.0f;
    #pragma unroll
    for (int j = 0; j < 4; ++j) { float dv = v[j] - mean; vs += dv * dv; }
    float var = block_sum1(vs, red, tid) * (1.0f / PDBIG);
    float inv = rsqrtf(var + 1e-5f);
    float4 g4 = *(const float4*)(g + i0);
    float4 b4 = *(const float4*)(bb + i0);
    float gv[4] = {g4.x, g4.y, g4.z, g4.w};
    float bv[4] = {b4.x, b4.y, b4.z, b4.w};
    unsigned short ho[4], lo_[4];
    #pragma unroll
    for (int j = 0; j < 4; ++j) {
        float y = (v[j] - mean) * inv * gv[j] + bv[j];
        split_u(y, ho[j], lo_[j]);
    }
    *(ushort4*)(epu + i0)        = make_ushort4(ho[0], ho[1], ho[2], ho[3]);
    *(ushort4*)(epu + 1024 + i0) = make_ushort4(lo_[0], lo_[1], lo_[2], lo_[3]);
}

// ---------------- pool ----------------
__global__ __launch_bounds__(256) void pst_pool1(
    const float* __restrict__ wvec, const unsigned short* __restrict__ pk,
    float* __restrict__ partial)
{
    int p = blockIdx.x, b = blockIdx.y, tid = threadIdx.x;
    float acc = 0.0f;
    for (int n = p * 64; n < p * 64 + 64; ++n) {
        float w = wvec[(long)b * PN + n];
        long row = (long)b * PN + n;
        float xv = b2f(pk[row * 512 + tid]) + b2f(pk[row * 512 + 256 + tid]);
        acc = fmaf(w, xv, acc);
    }
    partial[((long)b * 8 + p) * PDD + tid] = acc;
}

__global__ __launch_bounds__(256) void pst_pool2(
    const float* __restrict__ partial, const float* __restrict__ partiali,
    const float* __restrict__ ln_g, const float* __restrict__ ln_b,
    const float* __restrict__ out_W, const float* __restrict__ out_b,
    float* __restrict__ out)
{
    int b = blockIdx.x, tid = threadIdx.x;
    __shared__ float red[4];
    float acc = 0.0f;
    #pragma unroll
    for (int p = 0; p < 8; ++p)
        acc += partial[((long)b * 8 + p) * PDD + tid] + partiali[((long)b * 8 + p) * PDD + tid];
    float mean = block_sum1(acc, red, tid) * (1.0f / PDD);
    float dv = acc - mean;
    float var = block_sum1(dv * dv, red, tid) * (1.0f / PDD);
    float y = dv * rsqrtf(var + 1e-5f) * ln_g[tid] + ln_b[tid];
    float s = block_sum1(y * out_W[tid], red, tid);
    if (tid == 0) out[b] = s + out_b[0];
}

// ---------------- host ----------------
template<int MODE, int VAR>
static void launch_gbf(const __hip_bfloat16* A, const __hip_bfloat16* B, const float* bias,
                       float* C, __hip_bfloat16* P, int M, int Nw, int K,
                       long sA, long sB, long sC, int batch, hipStream_t st)
{
    dim3 grid(Nw / 128, M / 128, batch);
    pst_gemm_bf16<MODE, VAR><<<grid, dim3(256), 0, st>>>(A, B, bias, C, P, K, Nw, sA, sB, sC);
}

extern "C" void kernel_launch(void* const* d_in, const int* in_sizes, int n_in,
                              void* d_out, int out_size, void* d_ws, size_t ws_size,
                              hipStream_t stream)
{
    const float* features  = (const float*)d_in[0];
    const float* atom_fea  = (const float*)d_in[1];
    const float* comp_W    = (const float*)d_in[2];
    const float* comp_b    = (const float*)d_in[3];
    const float* emb_W     = (const float*)d_in[4];
    const float* emb_b     = (const float*)d_in[5];
    const float* ln_g      = (const float*)d_in[6];
    const float* ln_b      = (const float*)d_in[7];
    const float* enc_emb_W = (const float*)d_in[8];
    const float* enc_emb_b = (const float*)d_in[9];
    const float* enc_Wq_W  = (const float*)d_in[10];
    const float* enc_Wq_b  = (const float*)d_in[11];
    const float* enc_Wk_W  = (const float*)d_in[12];
    const float* enc_Wk_b  = (const float*)d_in[13];
    const float* enc_Wv_W  = (const float*)d_in[14];
    const float* enc_Wv_b  = (const float*)d_in[15];
    const float* enc_inq_W = (const float*)d_in[16];
    const float* enc_inq_b = (const float*)d_in[17];
    const float* enc_ink_W = (const float*)d_in[18];
    const float* enc_ink_b = (const float*)d_in[19];
    const float* enc_ln_g  = (const float*)d_in[20];
    const float* enc_ln_b  = (const float*)d_in[21];
    const float* enc_out_W = (const float*)d_in[22];
    const float* enc_out_b = (const float*)d_in[23];
    const float* out_W     = (const float*)d_in[24];
    const float* out_b     = (const float*)d_in[25];

    // ----- persistent workspace (floats); WqkvT now SINGLE (hi-only) -----
    float* ws = (float*)d_ws;
    size_t off = 0;
    unsigned short* xpk  = (unsigned short*)(ws + off); off += (size_t)PB * PN * 512 / 2;
    __hip_bfloat16* WembT = (__hip_bfloat16*)(ws + off); off += (size_t)PL * 1024 * 512 / 2;
    __hip_bfloat16* WqkvT = (__hip_bfloat16*)(ws + off); off += (size_t)PL * 3072 * 1024 / 2;  // single
    __hip_bfloat16* WoutT2 = (__hip_bfloat16*)(ws + off); off += (size_t)256 * 2048 / 2;
    __hip_bfloat16* WoeT  = (__hip_bfloat16*)(ws + off); off += (size_t)2 * 1024 * 2048 / 2;
    float* bqkv  = ws + off; off += (size_t)PL * 3072;
    float* boe   = ws + off; off += (size_t)2 * PDBIG;
    float* atomP = ws + off; off += (size_t)100 * PDD;
    float* S0v   = ws + off; off += (size_t)PNDIST * PDD;
    float* S1v   = ws + off; off += (size_t)PNDIST * PDD;
    float* Cv    = ws + off; off += PDD;
    float* partial  = ws + off; off += (size_t)PB * 8 * PDD;
    float* partiali = ws + off; off += (size_t)PB * 8 * PDD;
    float* wvec  = ws + off; off += (size_t)PB * PN;
    size_t persistf = off;

    const size_t PRE_FL = (size_t)3 * 1024 * 2048 / 2 * 2 + (size_t)3 * 1024 * 1024;
    // chunk rows (floats): B0 1024 + B1 1024 + qp 512 (Apack overlays) + kp 512 +
    // vpT 512 + Spack/attb 1024 = 4608
    const size_t ROW_FL = 4608;
    int CB = 64;
    while (CB > 1) {
        size_t M = (size_t)CB * PN;
        size_t region = M * ROW_FL;
        if (region < PRE_FL) region = PRE_FL;
        if ((persistf + region) * sizeof(float) <= ws_size) break;
        CB >>= 1;
    }
    const size_t M = (size_t)CB * PN;

    float* base = ws + persistf;
    __hip_bfloat16* pA = (__hip_bfloat16*)base;
    __hip_bfloat16* pB = (__hip_bfloat16*)(base + 3145728);
    float* Wtmp3 = base + 6291456;
    __hip_bfloat16* B0    = (__hip_bfloat16*)(base);             // epack ping
    __hip_bfloat16* B1    = (__hip_bfloat16*)(base + M * 1024);  // epack pong / oe target
    __hip_bfloat16* qp    = (__hip_bfloat16*)(base + M * 2048);  // q single per-head; Apack overlays
    __hip_bfloat16* kp    = (__hip_bfloat16*)(base + M * 2560);  // k single per-head
    __hip_bfloat16* vpT   = (__hip_bfloat16*)(base + M * 3072);  // v single transposed
    unsigned short* Spack = (unsigned short*)(base + M * 3584);  // S single; attb overlays
    float* attb           = base + M * 3584;

    // ----- precompute -----
    pst_atomproj<<<dim3(100), 256, 0, stream>>>(atom_fea, comp_W, atomP);
    pst_embW_reduce<<<dim3(PNDIST), 256, 0, stream>>>(emb_W, S0v, S1v);
    pst_embW_const<<<dim3(1), 256, 0, stream>>>(emb_W, comp_b, emb_b, Cv);
    pst_wext<<<dim3(PB * PN / 256), 256, 0, stream>>>(features, wvec);

    const long WS = 1024L * 1024;
    const long WE = 256L * 1024;
    const long SQK = 3072L * 1024;   // WqkvT per-layer stride (single bf16)
    pst_packT_wL<<<dim3(WE / 256, 3), 256, 0, stream>>>(enc_emb_W, WembT, 256, 1024, WE, 1024L * 512);
    // q combined (split-bf16 3-pass GEMM for the f32 combine; result packed single)
    pst_pack_rows<<<dim3(3 * WS / 256), 256, 0, stream>>>(enc_Wq_W, pA, 10);
    pst_packT_wL<<<dim3(WS / 256, 3), 256, 0, stream>>>(enc_inq_W, pB, 1024, 1024, WS, 1024L * 2048);
    launch_gbf<0, 0>(pA, pB, nullptr, Wtmp3, nullptr,
                     1024, 1024, 1024, 1024L * 2048, 1024L * 2048, WS, 3, stream);
    pst_packT_single<<<dim3(WS / 256, 3), 256, 0, stream>>>(Wtmp3, WqkvT, 1024, 1024, WS, SQK);
    pst_bias_comb<<<dim3(4, 3), 256, 0, stream>>>(enc_Wq_b, enc_inq_W, enc_inq_b, bqkv, 0);
    // k combined
    pst_pack_rows<<<dim3(3 * WS / 256), 256, 0, stream>>>(enc_Wk_W, pA, 10);
    pst_packT_wL<<<dim3(WS / 256, 3), 256, 0, stream>>>(enc_ink_W, pB, 1024, 1024, WS, 1024L * 2048);
    launch_gbf<0, 0>(pA, pB, nullptr, Wtmp3, nullptr,
                     1024, 1024, 1024, 1024L * 2048, 1024L * 2048, WS, 3, stream);
    pst_packT_single<<<dim3(WS / 256, 3), 256, 0, stream>>>(Wtmp3, WqkvT + 1024L * 1024, 1024, 1024, WS, SQK);
    pst_bias_comb<<<dim3(4, 3), 256, 0, stream>>>(enc_Wk_b, enc_ink_W, enc_ink_b, bqkv, 1024);
    // v pack (single) + bias
    pst_packT_single<<<dim3(WS / 256, 3), 256, 0, stream>>>(enc_Wv_W, WqkvT + 2048L * 1024, 1024, 1024, WS, SQK);
    pst_vbias<<<dim3(4, 3), 256, 0, stream>>>(enc_Wv_b, bqkv);
    // out pack (layer 2 only, split for VAR 3)
    pst_packT_wL<<<dim3(WE / 256, 1), 256, 0, stream>>>(enc_out_W + 2 * WE, WoutT2, 1024, 256, WE, 256L * 2048);
    // fused Woe (split for VAR 3)
    pst_pack_rows<<<dim3(2 * WE / 256), 256, 0, stream>>>(enc_out_W, pA, 8);
    launch_gbf<0, 0>(pA, WembT + 1024L * 512, nullptr, Wtmp3, nullptr,
                     1024, 1024, 256, 1024L * 512, 1024L * 512, WS, 2, stream);
    pst_packT_wL<<<dim3(WS / 256, 2), 256, 0, stream>>>(Wtmp3, WoeT, 1024, 1024, WS, 1024L * 2048);
    pst_bias_oe<<<dim3(4, 2), 256, 0, stream>>>(enc_out_b, enc_emb_W, enc_emb_b, boe);

    // ----- embedding + pre-pool of x_init (reads xpk before encoder mutates it) -----
    pst_embed16<<<dim3(PB * PN / 16), 256, 0, stream>>>(
        features, atomP, S0v, S1v, Cv, ln_g, ln_b, xpk);
    pst_pool1<<<dim3(8, PB), 256, 0, stream>>>(wvec, xpk, partiali);

    hipFuncSetAttribute((const void*)pst_gemm_qkv256,
                        hipFuncAttributeMaxDynamicSharedMemorySize, 65536);

    // ----- encoder layers, chunked -----
    for (int cb0 = 0; cb0 < PB; cb0 += CB) {
        const int Mi = (int)M;
        __hip_bfloat16* xps = (__hip_bfloat16*)xpk + (size_t)cb0 * PN * 512;
        __hip_bfloat16* eP = B0;
        __hip_bfloat16* qP2 = B1;
        launch_gbf<4, 3>(xps, WembT, enc_emb_b, nullptr, eP,
                         Mi, PDBIG, PDD, 0, 0, 0, 1, stream);
        for (int l = 0; l < PL; ++l) {
            __hip_bfloat16* Apack = qp;   // overlays qp (dead after S-GEMM)
            {
                dim3 grid(3072 / 256, Mi / 256, 1);
                pst_gemm_qkv256<<<grid, dim3(512), 65536, stream>>>(
                    eP, WqkvT + (size_t)l * SQK, bqkv + (size_t)l * 3072,
                    qp, kp, vpT, PDBIG);
            }
            launch_gbf<5, 1>(qp, kp, nullptr, nullptr, (__hip_bfloat16*)Spack,
                             512, 512, 256, 512L * 256, 512L * 256, 512L * 512,
                             CB * 4, stream);
            pst_attnSM<<<dim3(CB * 64), 256, 0, stream>>>(Spack, wvec, Apack, cb0);
            // att = A @ v: single x single, 1-pass (K=512)
            launch_gbf<0, 1>(Apack, vpT, nullptr, attb, nullptr,
                             512, PDBIG, 512, 512L * 512, 1024L * 512, 512L * 1024,
                             CB, stream);
            pst_spln<<<dim3(Mi), 256, 0, stream>>>(
                attb, eP, enc_ln_g + (size_t)l * PDBIG, enc_ln_b + (size_t)l * PDBIG);
            if (l < PL - 1) {
                launch_gbf<4, 3>(eP, WoeT + (size_t)l * 1024 * 2048, boe + (size_t)l * PDBIG,
                                 nullptr, qP2, Mi, PDBIG, PDBIG, 0, 0, 0, 1, stream);
                __hip_bfloat16* t = eP; eP = qP2; qP2 = t;
            } else {
                launch_gbf<4, 3>(eP, WoutT2, enc_out_b + 2 * (size_t)PDD,
                                 nullptr, xps, Mi, PDD, PDBIG, 0, 0, 0, 1, stream);
            }
        }
    }

    // ----- pool -----
    pst_pool1<<<dim3(8, PB), 256, 0, stream>>>(wvec, xpk, partial);
    pst_pool2<<<dim3(PB), 256, 0, stream>>>(partial, partiali, ln_g, ln_b, out_W, out_b,
                                            (float*)d_out);
}

// Round 22
// 3224.133 us; speedup vs baseline: 1.0308x; 1.0308x over previous
//
#include <hip/hip_runtime.h>
#include <hip/hip_bf16.h>

// ---------------- problem constants ----------------
#define PB 64      // batch
#define PN 512     // set size
#define PFEA 102
#define PE 10
#define PDD 256    // d
#define PH 4
#define PDBIG 1024 // D = d*H
#define PL 3
#define PNDIST 100

typedef __attribute__((ext_vector_type(8))) short s8b;   // 8 bf16 (4 VGPRs)
typedef __attribute__((ext_vector_type(4))) float f4;    // 4 fp32 acc

typedef __attribute__((address_space(1))) const void gvoid_t;
typedef __attribute__((address_space(3))) void lvoid_t;
#define GLDS16(g, s) __builtin_amdgcn_global_load_lds((gvoid_t*)(g), (lvoid_t*)(s), 16, 0, 0)

union bfu { __hip_bfloat16 b; unsigned short u; };

__device__ __forceinline__ float b2f(unsigned short u) {
    return __uint_as_float((unsigned int)u << 16);
}
__device__ __forceinline__ unsigned short f2bu(float v) {
    bfu c; c.b = __float2bfloat16(v); return c.u;
}
__device__ __forceinline__ void split_bf16(float v, __hip_bfloat16& hi, __hip_bfloat16& lo) {
    hi = __float2bfloat16(v);
    lo = __float2bfloat16(v - __bfloat162float(hi));
}
__device__ __forceinline__ void split_u(float v, unsigned short& hu, unsigned short& lu) {
    __hip_bfloat16 h, l; split_bf16(v, h, l);
    bfu c; c.b = h; hu = c.u; c.b = l; lu = c.u;
}

// ---------------- reduction helpers ----------------
__device__ __forceinline__ float block_sum1(float v, float* red, int tid) {
    #pragma unroll
    for (int off = 32; off >= 1; off >>= 1) v += __shfl_xor(v, off);
    __syncthreads();
    if ((tid & 63) == 0) red[tid >> 6] = v;
    __syncthreads();
    return red[0] + red[1] + red[2] + red[3];
}

template<int NR, bool MAXOP>
__device__ __forceinline__ void block_redN(float* v, float* red, int tid) {
    #pragma unroll
    for (int off = 32; off >= 1; off >>= 1) {
        #pragma unroll
        for (int r = 0; r < NR; ++r) {
            float o = __shfl_xor(v[r], off);
            v[r] = MAXOP ? fmaxf(v[r], o) : (v[r] + o);
        }
    }
    __syncthreads();
    if ((tid & 63) == 0) {
        #pragma unroll
        for (int r = 0; r < NR; ++r) red[(tid >> 6) * NR + r] = v[r];
    }
    __syncthreads();
    #pragma unroll
    for (int r = 0; r < NR; ++r) {
        float a = red[r], b = red[NR + r], c = red[2 * NR + r], d = red[3 * NR + r];
        v[r] = MAXOP ? fmaxf(fmaxf(a, b), fmaxf(c, d)) : ((a + b) + (c + d));
    }
    __syncthreads();
}

// ---------------- precompute kernels ----------------
__global__ __launch_bounds__(256) void pst_atomproj(
    const float* __restrict__ atom_fea, const float* __restrict__ comp_W,
    float* __restrict__ atomP)
{
    int a = blockIdx.x, tid = threadIdx.x;
    __shared__ float af[92];
    if (tid < 92) af[tid] = atom_fea[a * 92 + tid];
    __syncthreads();
    float s = 0.0f;
    #pragma unroll 4
    for (int k = 0; k < 92; ++k) s = fmaf(af[k], comp_W[k * PDD + tid], s);
    atomP[a * PDD + tid] = s;
}

__global__ __launch_bounds__(256) void pst_embW_reduce(
    const float* __restrict__ emb_W, float* __restrict__ S0, float* __restrict__ S1)
{
    int f = blockIdx.x, tid = threadIdx.x;
    float s0 = 0.0f, s1 = 0.0f;
    #pragma unroll
    for (int t = 0; t < PE; ++t) {
        float w = emb_W[(f * PE + t) * PDD + tid];
        float tf = (float)t / (float)PE;
        s0 += w;
        s1 = fmaf(2.0f * tf, w, s1);
    }
    S0[f * PDD + tid] = s0;
    S1[f * PDD + tid] = s1;
}

__global__ __launch_bounds__(256) void pst_embW_const(
    const float* __restrict__ emb_W, const float* __restrict__ comp_b,
    const float* __restrict__ emb_b, float* __restrict__ Cv)
{
    int tid = threadIdx.x;
    float s = comp_b[tid] + emb_b[tid];
    for (int m = 0; m < PNDIST * PE; ++m) {
        float tf = (float)(m % PE) / (float)PE;
        s = fmaf(tf * tf, emb_W[m * PDD + tid], s);
    }
    Cv[tid] = s;
}

__global__ __launch_bounds__(256) void pst_wext(
    const float* __restrict__ features, float* __restrict__ wvec)
{
    long i = (long)blockIdx.x * 256 + threadIdx.x;
    wvec[i] = features[i * PFEA];
}

// ---------------- embed: 16 rows/block, f-loop unrolled x4 ----------------
__global__ __launch_bounds__(256) void pst_embed16(
    const float* __restrict__ features, const float* __restrict__ atomP,
    const float* __restrict__ S0, const float* __restrict__ S1,
    const float* __restrict__ Cv, const float* __restrict__ ln_g,
    const float* __restrict__ ln_b, unsigned short* __restrict__ xpk)
{
    int r0 = blockIdx.x * 16, tid = threadIdx.x;
    __shared__ float uv[16][PNDIST];
    __shared__ int idxs[16];
    __shared__ float red[64];
    for (int m = tid; m < 16 * PNDIST; m += 256) {
        int r = m / PNDIST, f = m - r * PNDIST;
        uv[r][f] = 1.0f - features[(long)(r0 + r) * PFEA + 1 + f];
    }
    if (tid < 16) idxs[tid] = (int)features[(long)(r0 + tid) * PFEA + PFEA - 1];
    __syncthreads();

    float acc[16];
    float cv = Cv[tid];
    #pragma unroll
    for (int r = 0; r < 16; ++r) acc[r] = cv + atomP[idxs[r] * PDD + tid];
    for (int f = 0; f < PNDIST; f += 4) {
        float s0v[4], s1v[4];
        #pragma unroll
        for (int u = 0; u < 4; ++u) {
            s0v[u] = S0[(f + u) * PDD + tid];
            s1v[u] = S1[(f + u) * PDD + tid];
        }
        #pragma unroll
        for (int u = 0; u < 4; ++u) {
            #pragma unroll
            for (int r = 0; r < 16; ++r) {
                float uu = uv[r][f + u];
                acc[r] = fmaf(uu, fmaf(uu, s0v[u], s1v[u]), acc[r]);
            }
        }
    }
    float mean[16];
    #pragma unroll
    for (int r = 0; r < 16; ++r) mean[r] = acc[r];
    block_redN<16, false>(mean, red, tid);
    float var[16], dv[16];
    #pragma unroll
    for (int r = 0; r < 16; ++r) { mean[r] *= (1.0f / PDD); dv[r] = acc[r] - mean[r]; var[r] = dv[r] * dv[r]; }
    block_redN<16, false>(var, red, tid);
    #pragma unroll
    for (int r = 0; r < 16; ++r) {
        float y = dv[r] * rsqrtf(var[r] * (1.0f / PDD) + 1e-5f) * ln_g[tid] + ln_b[tid];
        long row = (long)(r0 + r);
        unsigned short hu, lu; split_u(y, hu, lu);
        xpk[row * 512 + tid] = hu;
        xpk[row * 512 + 256 + tid] = lu;
    }
}

// ---------------- 128-tile bf16 MFMA GEMM (BK=64, XOR-swizzled LDS) ----------
// VAR 0: split x split, 3-pass. VAR 1: single x single, 1-pass.
// VAR 3: split x split, 2-pass (Ah Bh + Al Bh) — trunk precision.
// MODE 0: C f32. MODE 4: P split row-pack. MODE 5: P single pack.
template<int MODE, int VAR>
__global__ __launch_bounds__(256) void pst_gemm_bf16(
    const __hip_bfloat16* __restrict__ Ap, const __hip_bfloat16* __restrict__ Bp,
    const float* __restrict__ bias, float* __restrict__ C,
    __hip_bfloat16* __restrict__ P,
    int K, int Nw, long strideA, long strideB, long strideC)
{
    const int lda = (VAR == 1) ? K : 2 * K;
    const int ldb = (VAR == 1) ? K : 2 * K;
    int bz = blockIdx.z;
    Ap += (long)bz * strideA; Bp += (long)bz * strideB;
    if (MODE == 0) C += (long)bz * strideC;
    else P += (long)bz * strideC;

    // T1v2: 2D-rectangular XCD swizzle
    int gx = gridDim.x, gy = gridDim.y;
    int lin = blockIdx.y * gx + blockIdx.x;
    int m0, n0;
    if (((gy & 3) == 0) && ((gx & 1) == 0)) {
        int rm = gy >> 2, rn = gx >> 1;
        int xcd = lin & 7, t = lin >> 3;
        int lm = t % rm, ln = t / rm;
        m0 = ((xcd >> 1) * rm + lm) * 128;
        n0 = ((xcd & 1) * rn + ln) * 128;
    } else {
        m0 = blockIdx.y * 128; n0 = blockIdx.x * 128;
    }

    __shared__ __hip_bfloat16 As[128 * 64];
    __shared__ __hip_bfloat16 Bs[128 * 64];

    int tid = threadIdx.x;
    int w = tid >> 6, l = tid & 63;
    int lr = l & 15, kb = l >> 4;
    int wm = (w >> 1) * 64, wn = (w & 1) * 64;
    int srow = tid >> 3;
    int sg = tid & 7;

    f4 acc[4][4] = {};

    const int K3 = (VAR == 0) ? 3 * K : ((VAR == 3) ? 2 * K : K);
    for (int k0 = 0; k0 < K3; k0 += 64) {
        int kA, kB;
        if (VAR == 0) { kA = (k0 < 2 * K) ? k0 : k0 - 2 * K; kB = (k0 < K) ? k0 : k0 - K; }
        else if (VAR == 3) { kA = k0; kB = (k0 < K) ? k0 : k0 - K; }
        else { kA = k0; kB = k0; }
        #pragma unroll
        for (int s = 0; s < 4; ++s) {
            int r = s * 32 + srow;
            int gsrc = sg ^ (r & 7);
            const __hip_bfloat16* ga = Ap + (long)(m0 + r) * lda + kA + gsrc * 8;
            const __hip_bfloat16* gb = Bp + (long)(n0 + r) * ldb + kB + gsrc * 8;
            GLDS16(ga, As + s * 2048 + w * 512);
            GLDS16(gb, Bs + s * 2048 + w * 512);
        }
        __syncthreads();

        #pragma unroll
        for (int kh = 0; kh < 2; ++kh) {
            s8b af[4], bf[4];
            #pragma unroll
            for (int f = 0; f < 4; ++f) {
                int ra = wm + f * 16 + lr;
                int rb = wn + f * 16 + lr;
                int gr = kh * 4 + kb;
                af[f] = *(const s8b*)(As + ra * 64 + ((gr ^ (ra & 7)) * 8));
                bf[f] = *(const s8b*)(Bs + rb * 64 + ((gr ^ (rb & 7)) * 8));
            }
            #pragma unroll
            for (int i = 0; i < 4; ++i)
                #pragma unroll
                for (int j = 0; j < 4; ++j)
                    acc[i][j] = __builtin_amdgcn_mfma_f32_16x16x32_bf16(af[i], bf[j], acc[i][j], 0, 0, 0);
        }
        __syncthreads();
    }

    // C/D layout: col=lane&15, row=(lane>>4)*4+reg [verified m89/m91]
    #pragma unroll
    for (int i = 0; i < 4; ++i) {
        #pragma unroll
        for (int j = 0; j < 4; ++j) {
            int nbase = n0 + wn + j * 16 + lr;
            int mbase = m0 + wm + i * 16 + kb * 4;
            #pragma unroll
            for (int r = 0; r < 4; ++r) {
                int m = mbase + r;
                int n = nbase;
                float val = acc[i][j][r] + (bias ? bias[n] : 0.0f);
                if (MODE == 0) {
                    C[(long)m * Nw + n] = val;
                } else if (MODE == 4) {
                    __hip_bfloat16 hi, lo; split_bf16(val, hi, lo);
                    long b = (long)m * (2 * Nw) + n;
                    P[b] = hi; P[b + Nw] = lo;
                } else { // MODE 5: single pack
                    P[(long)m * Nw + n] = __float2bfloat16(val);
                }
            }
        }
    }
}

// ---------------- 256-tile 8-wave qkv GEMM (R21: BK=64 proven-conflict-free,
// dbuf 128KB, 1 sync/tile; A split pack hi-read lda=2K, B SINGLE pack ldb=K) ----
__global__ __launch_bounds__(512) void pst_gemm_qkv256(
    const __hip_bfloat16* __restrict__ Ap, const __hip_bfloat16* __restrict__ Bp,
    const float* __restrict__ bias,
    __hip_bfloat16* __restrict__ Pq, __hip_bfloat16* __restrict__ Pk,
    __hip_bfloat16* __restrict__ Pv, int K)
{
    extern __shared__ __hip_bfloat16 lds[];
    __hip_bfloat16* Asd = lds;              // 2 x 16384 elems (256x64 per buf)
    __hip_bfloat16* Bsd = lds + 32768;      // 2 x 16384 elems

    const int lda = 2 * K;   // A split pack: read hi half only
    const int ldb = K;       // B single pack

    int gx = gridDim.x, gy = gridDim.y;
    int lin = blockIdx.y * gx + blockIdx.x;
    int m0, n0;
    if (((gy & 3) == 0) && ((gx & 1) == 0)) {
        int rm = gy >> 2, rn = gx >> 1;
        int xcd = lin & 7, t = lin >> 3;
        int lm = t % rm, ln = t / rm;
        m0 = ((xcd >> 1) * rm + lm) * 256;
        n0 = ((xcd & 1) * rn + ln) * 256;
    } else {
        m0 = blockIdx.y * 256; n0 = blockIdx.x * 256;
    }

    int tid = threadIdx.x;
    int w = tid >> 6, l = tid & 63;
    int lr = l & 15, kb = l >> 4;
    int wm = (w >> 2) * 128;
    int wn = (w & 3) * 64;
    int r6 = tid >> 3;                      // staging row within 64-chunk
    int g  = tid & 7;                       // staging granule (8 per 64-col row)

    f4 acc[8][4] = {};

    const int nt = K / 64;

    auto stage = [&](int tIdx, int buf) {
        int k0 = tIdx * 64;
        #pragma unroll
        for (int i = 0; i < 4; ++i) {
            int r = i * 64 + r6;
            int gs = g ^ (r & 7);
            GLDS16(Ap + (long)(m0 + r) * lda + k0 + gs * 8,
                   Asd + buf * 16384 + i * 4096 + w * 512);
            GLDS16(Bp + (long)(n0 + r) * ldb + k0 + gs * 8,
                   Bsd + buf * 16384 + i * 4096 + w * 512);
        }
    };

    stage(0, 0);
    __syncthreads();

    for (int t = 0; t < nt; ++t) {
        int cur = t & 1;
        if (t + 1 < nt) stage(t + 1, cur ^ 1);

        s8b bfr[4][2];
        #pragma unroll
        for (int fc = 0; fc < 4; ++fc) {
            int rb = wn + fc * 16 + lr;
            #pragma unroll
            for (int kh = 0; kh < 2; ++kh)
                bfr[fc][kh] = *(const s8b*)(Bsd + cur * 16384 + rb * 64 +
                                            (((kh * 4 + kb) ^ (rb & 7)) * 8));
        }
        #pragma unroll
        for (int q = 0; q < 4; ++q) {
            s8b afr[2][2];
            #pragma unroll
            for (int d = 0; d < 2; ++d) {
                int ra = wm + (q * 2 + d) * 16 + lr;
                #pragma unroll
                for (int kh = 0; kh < 2; ++kh)
                    afr[d][kh] = *(const s8b*)(Asd + cur * 16384 + ra * 64 +
                                               (((kh * 4 + kb) ^ (ra & 7)) * 8));
            }
            __builtin_amdgcn_s_setprio(1);
            #pragma unroll
            for (int d = 0; d < 2; ++d)
                #pragma unroll
                for (int fc = 0; fc < 4; ++fc)
                    #pragma unroll
                    for (int kh = 0; kh < 2; ++kh)
                        acc[q * 2 + d][fc] = __builtin_amdgcn_mfma_f32_16x16x32_bf16(
                            afr[d][kh], bfr[fc][kh], acc[q * 2 + d][fc], 0, 0, 0);
            __builtin_amdgcn_s_setprio(0);
        }
        __syncthreads();
    }

    // epilogue: q,k single per-head packs; v single transposed pack (8B writes)
    #pragma unroll
    for (int i = 0; i < 8; ++i) {
        #pragma unroll
        for (int j = 0; j < 4; ++j) {
            int nbase = n0 + wn + j * 16 + lr;
            int mbase = m0 + wm + i * 16 + kb * 4;
            if ((nbase >> 10) == 2) {
                int np = nbase & 1023;
                unsigned short hu[4];
                #pragma unroll
                for (int r = 0; r < 4; ++r)
                    hu[r] = f2bu(acc[i][j][r] + bias[nbase]);
                int bb = mbase >> 9, rr0 = mbase & 511;
                unsigned short* pv = (unsigned short*)Pv + ((long)bb * PDBIG + np) * 512;
                *(ushort4*)(pv + rr0) = make_ushort4(hu[0], hu[1], hu[2], hu[3]);
            } else {
                #pragma unroll
                for (int r = 0; r < 4; ++r) {
                    int m = mbase + r;
                    int n = nbase;
                    float val = acc[i][j][r] + bias[n];
                    int bb = m >> 9, rr = m & 511;
                    int reg2 = n >> 10, np = n & 1023;
                    __hip_bfloat16* dst = (reg2 == 0) ? Pq : Pk;
                    int h = np >> 8, kk = np & 255;
                    dst[(((long)bb * 4 + h) * 512 + rr) * 256 + kk] = __float2bfloat16(val);
                }
            }
        }
    }
}

// ---------------- pack helpers ----------------
__global__ __launch_bounds__(256) void pst_pack_rows(
    const float* __restrict__ src, __hip_bfloat16* __restrict__ dst, int kshift)
{
    long i = (long)blockIdx.x * 256 + threadIdx.x;
    int K = 1 << kshift;
    long m = i >> kshift; int k = (int)(i & (K - 1));
    float v = src[i];
    __hip_bfloat16 hi, lo; split_bf16(v, hi, lo);
    long b = (m << (kshift + 1)) + k;
    dst[b] = hi; dst[b + K] = lo;
}

__global__ __launch_bounds__(256) void pst_packT_wL(
    const float* __restrict__ W, __hip_bfloat16* __restrict__ dst,
    int K, int N, long sSrc, long sDst)
{
    int lyr = blockIdx.y;
    long i = (long)blockIdx.x * 256 + threadIdx.x;
    int k = (int)(i / N), n = (int)(i - (long)k * N);
    float v = W[lyr * sSrc + i];
    __hip_bfloat16 hi, lo; split_bf16(v, hi, lo);
    long b = lyr * sDst + (long)n * (2 * K) + k;
    dst[b] = hi; dst[b + K] = lo;
}

// transpose pack, hi-only (single): W [L][K][N] f32 -> dst [L][N][K] bf16
__global__ __launch_bounds__(256) void pst_packT_single(
    const float* __restrict__ W, __hip_bfloat16* __restrict__ dst,
    int K, int N, long sSrc, long sDst)
{
    int lyr = blockIdx.y;
    long i = (long)blockIdx.x * 256 + threadIdx.x;
    int k = (int)(i / N), n = (int)(i - (long)k * N);
    float v = W[lyr * sSrc + i];
    dst[lyr * sDst + (long)n * K + k] = __float2bfloat16(v);
}

__global__ __launch_bounds__(256) void pst_bias_comb(
    const float* __restrict__ b1, const float* __restrict__ W2,
    const float* __restrict__ b2, float* __restrict__ out, int outOff)
{
    int lyr = blockIdx.y;
    int n = blockIdx.x * 256 + threadIdx.x;
    const float* b1l = b1 + (size_t)lyr * PDBIG;
    const float* W2l = W2 + (size_t)lyr * PDBIG * PDBIG;
    float s = b2[(size_t)lyr * PDBIG + n];
    for (int k2 = 0; k2 < PDBIG; ++k2)
        s = fmaf(b1l[k2], W2l[(long)k2 * PDBIG + n], s);
    out[(size_t)lyr * 3072 + outOff + n] = s;
}

__global__ __launch_bounds__(256) void pst_bias_oe(
    const float* __restrict__ bout, const float* __restrict__ Wemb,
    const float* __restrict__ bemb, float* __restrict__ boe)
{
    int lyr = blockIdx.y;
    int n = blockIdx.x * 256 + threadIdx.x;
    const float* b1 = bout + (size_t)lyr * PDD;
    const float* W  = Wemb + (size_t)(lyr + 1) * PDD * PDBIG;
    float s = bemb[(size_t)(lyr + 1) * PDBIG + n];
    #pragma unroll 4
    for (int k = 0; k < PDD; ++k)
        s = fmaf(b1[k], W[(long)k * PDBIG + n], s);
    boe[(size_t)lyr * PDBIG + n] = s;
}

__global__ __launch_bounds__(256) void pst_vbias(
    const float* __restrict__ src, float* __restrict__ out)
{
    int lyr = blockIdx.y;
    int i = blockIdx.x * 256 + threadIdx.x;
    out[(size_t)lyr * 3072 + 2048 + i] = src[(size_t)lyr * PDBIG + i];
}

// ---------------- attention softmax (no mask; single S/A) ----------
__global__ __launch_bounds__(256) void pst_attnSM(
    const unsigned short* __restrict__ Sp, const float* __restrict__ wvec,
    __hip_bfloat16* __restrict__ Apack, int bGlobBase)
{
    int blk = blockIdx.x;
    int bLoc = blk >> 6;
    int q0 = (blk & 63) << 3;
    int tid = threadIdx.x;
    int w = tid >> 6, lane = tid & 63;
    int r0 = q0 + w * 2;
    int bGlob = bGlobBase + bLoc;

    float wcol[8];
    #pragma unroll
    for (int j = 0; j < 8; ++j)
        wcol[j] = wvec[(long)bGlob * PN + lane + 64 * j];
    const float scale = 0.0625f;
    float pacc[2][8] = {};

    for (int h = 0; h < PH; ++h) {
        const unsigned short* Sh = Sp + (((long)(bLoc * 4 + h)) * 512 + r0) * 512;
        #pragma unroll
        for (int rr = 0; rr < 2; ++rr) {
            float s[8]; float mx = -1e30f;
            #pragma unroll
            for (int j = 0; j < 8; ++j) {
                float a = b2f(Sh[(long)rr * 512 + lane + 64 * j]) * scale;
                s[j] = a; mx = fmaxf(mx, a);
            }
            #pragma unroll
            for (int off = 32; off >= 1; off >>= 1) mx = fmaxf(mx, __shfl_xor(mx, off));
            float sum = 0.0f;
            #pragma unroll
            for (int j = 0; j < 8; ++j) { s[j] = __expf(s[j] - mx); sum += s[j]; }
            #pragma unroll
            for (int off = 32; off >= 1; off >>= 1) sum += __shfl_xor(sum, off);
            float inv = 1.0f / sum;
            #pragma unroll
            for (int j = 0; j < 8; ++j) pacc[rr][j] = fmaf(s[j], inv, pacc[rr][j]);
        }
    }
    #pragma unroll
    for (int rr = 0; rr < 2; ++rr) {
        float asum = 0.0f;
        #pragma unroll
        for (int j = 0; j < 8; ++j) { pacc[rr][j] *= wcol[j]; asum += pacc[rr][j]; }
        #pragma unroll
        for (int off = 32; off >= 1; off >>= 1) asum += __shfl_xor(asum, off);
        float inv = 1.0f / asum;
        long rowb = ((long)bLoc * PN + r0 + rr) * 512;
        #pragma unroll
        for (int j = 0; j < 8; ++j) {
            int c = lane + 64 * j;
            Apack[rowb + c] = __float2bfloat16(pacc[rr][j] * inv);
        }
    }
}

// ---------------- spln ----------------
__global__ __launch_bounds__(256) void pst_spln(
    const float* __restrict__ att, __hip_bfloat16* __restrict__ ep,
    const float* __restrict__ g, const float* __restrict__ bb)
{
    int r = blockIdx.x, tid = threadIdx.x;
    __shared__ float red[4];
    int i0 = tid * 4;
    unsigned short* epu = (unsigned short*)ep + (long)r * 2048;
    ushort4 h4 = *(const ushort4*)(epu + i0);
    ushort4 l4 = *(const ushort4*)(epu + 1024 + i0);
    float4 a4 = *(const float4*)(att + (long)r * 1024 + i0);
    float v[4];
    {
        float av[4] = {a4.x, a4.y, a4.z, a4.w};
        unsigned short hv[4] = {h4.x, h4.y, h4.z, h4.w};
        unsigned short lv[4] = {l4.x, l4.y, l4.z, l4.w};
        #pragma unroll
        for (int j = 0; j < 4; ++j) {
            float a = av[j];
            float sp = (a > 20.0f) ? a : log1pf(expf(a));
            v[j] = b2f(hv[j]) + b2f(lv[j]) + sp;
        }
    }
    float s = v[0] + v[1] + v[2] + v[3];
    float mean = block_sum1(s, red, tid) * (1.0f / PDBIG);
    float vs = 0.0f;
    #pragma unroll
    for (int j = 0; j < 4; ++j) { float dv = v[j] - mean; vs += dv * dv; }
    float var = block_sum1(vs, red, tid) * (1.0f / PDBIG);
    float inv = rsqrtf(var + 1e-5f);
    float4 g4 = *(const float4*)(g + i0);
    float4 b4 = *(const float4*)(bb + i0);
    float gv[4] = {g4.x, g4.y, g4.z, g4.w};
    float bv[4] = {b4.x, b4.y, b4.z, b4.w};
    unsigned short ho[4], lo_[4];
    #pragma unroll
    for (int j = 0; j < 4; ++j) {
        float y = (v[j] - mean) * inv * gv[j] + bv[j];
        split_u(y, ho[j], lo_[j]);
    }
    *(ushort4*)(epu + i0)        = make_ushort4(ho[0], ho[1], ho[2], ho[3]);
    *(ushort4*)(epu + 1024 + i0) = make_ushort4(lo_[0], lo_[1], lo_[2], lo_[3]);
}

// ---------------- pool ----------------
__global__ __launch_bounds__(256) void pst_pool1(
    const float* __restrict__ wvec, const unsigned short* __restrict__ pk,
    float* __restrict__ partial)
{
    int p = blockIdx.x, b = blockIdx.y, tid = threadIdx.x;
    float acc = 0.0f;
    for (int n = p * 64; n < p * 64 + 64; ++n) {
        float w = wvec[(long)b * PN + n];
        long row = (long)b * PN + n;
        float xv = b2f(pk[row * 512 + tid]) + b2f(pk[row * 512 + 256 + tid]);
        acc = fmaf(w, xv, acc);
    }
    partial[((long)b * 8 + p) * PDD + tid] = acc;
}

__global__ __launch_bounds__(256) void pst_pool2(
    const float* __restrict__ partial, const float* __restrict__ partiali,
    const float* __restrict__ ln_g, const float* __restrict__ ln_b,
    const float* __restrict__ out_W, const float* __restrict__ out_b,
    float* __restrict__ out)
{
    int b = blockIdx.x, tid = threadIdx.x;
    __shared__ float red[4];
    float acc = 0.0f;
    #pragma unroll
    for (int p = 0; p < 8; ++p)
        acc += partial[((long)b * 8 + p) * PDD + tid] + partiali[((long)b * 8 + p) * PDD + tid];
    float mean = block_sum1(acc, red, tid) * (1.0f / PDD);
    float dv = acc - mean;
    float var = block_sum1(dv * dv, red, tid) * (1.0f / PDD);
    float y = dv * rsqrtf(var + 1e-5f) * ln_g[tid] + ln_b[tid];
    float s = block_sum1(y * out_W[tid], red, tid);
    if (tid == 0) out[b] = s + out_b[0];
}

// ---------------- host ----------------
template<int MODE, int VAR>
static void launch_gbf(const __hip_bfloat16* A, const __hip_bfloat16* B, const float* bias,
                       float* C, __hip_bfloat16* P, int M, int Nw, int K,
                       long sA, long sB, long sC, int batch, hipStream_t st)
{
    dim3 grid(Nw / 128, M / 128, batch);
    pst_gemm_bf16<MODE, VAR><<<grid, dim3(256), 0, st>>>(A, B, bias, C, P, K, Nw, sA, sB, sC);
}

extern "C" void kernel_launch(void* const* d_in, const int* in_sizes, int n_in,
                              void* d_out, int out_size, void* d_ws, size_t ws_size,
                              hipStream_t stream)
{
    const float* features  = (const float*)d_in[0];
    const float* atom_fea  = (const float*)d_in[1];
    const float* comp_W    = (const float*)d_in[2];
    const float* comp_b    = (const float*)d_in[3];
    const float* emb_W     = (const float*)d_in[4];
    const float* emb_b     = (const float*)d_in[5];
    const float* ln_g      = (const float*)d_in[6];
    const float* ln_b      = (const float*)d_in[7];
    const float* enc_emb_W = (const float*)d_in[8];
    const float* enc_emb_b = (const float*)d_in[9];
    const float* enc_Wq_W  = (const float*)d_in[10];
    const float* enc_Wq_b  = (const float*)d_in[11];
    const float* enc_Wk_W  = (const float*)d_in[12];
    const float* enc_Wk_b  = (const float*)d_in[13];
    const float* enc_Wv_W  = (const float*)d_in[14];
    const float* enc_Wv_b  = (const float*)d_in[15];
    const float* enc_inq_W = (const float*)d_in[16];
    const float* enc_inq_b = (const float*)d_in[17];
    const float* enc_ink_W = (const float*)d_in[18];
    const float* enc_ink_b = (const float*)d_in[19];
    const float* enc_ln_g  = (const float*)d_in[20];
    const float* enc_ln_b  = (const float*)d_in[21];
    const float* enc_out_W = (const float*)d_in[22];
    const float* enc_out_b = (const float*)d_in[23];
    const float* out_W     = (const float*)d_in[24];
    const float* out_b     = (const float*)d_in[25];

    // ----- persistent workspace (floats); WqkvT single (hi-only) -----
    float* ws = (float*)d_ws;
    size_t off = 0;
    unsigned short* xpk  = (unsigned short*)(ws + off); off += (size_t)PB * PN * 512 / 2;
    __hip_bfloat16* WembT = (__hip_bfloat16*)(ws + off); off += (size_t)PL * 1024 * 512 / 2;
    __hip_bfloat16* WqkvT = (__hip_bfloat16*)(ws + off); off += (size_t)PL * 3072 * 1024 / 2;  // single
    __hip_bfloat16* WoutT2 = (__hip_bfloat16*)(ws + off); off += (size_t)256 * 2048 / 2;
    __hip_bfloat16* WoeT  = (__hip_bfloat16*)(ws + off); off += (size_t)2 * 1024 * 2048 / 2;
    float* bqkv  = ws + off; off += (size_t)PL * 3072;
    float* boe   = ws + off; off += (size_t)2 * PDBIG;
    float* atomP = ws + off; off += (size_t)100 * PDD;
    float* S0v   = ws + off; off += (size_t)PNDIST * PDD;
    float* S1v   = ws + off; off += (size_t)PNDIST * PDD;
    float* Cv    = ws + off; off += PDD;
    float* partial  = ws + off; off += (size_t)PB * 8 * PDD;
    float* partiali = ws + off; off += (size_t)PB * 8 * PDD;
    float* wvec  = ws + off; off += (size_t)PB * PN;
    size_t persistf = off;

    const size_t PRE_FL = (size_t)3 * 1024 * 2048 / 2 * 2 + (size_t)3 * 1024 * 1024;
    // chunk rows (floats): B0 1024 + B1 1024 + qp 512 (Apack overlays) + kp 512 +
    // vpT 512 + Spack/attb 1024 = 4608
    const size_t ROW_FL = 4608;
    int CB = 64;
    while (CB > 1) {
        size_t M = (size_t)CB * PN;
        size_t region = M * ROW_FL;
        if (region < PRE_FL) region = PRE_FL;
        if ((persistf + region) * sizeof(float) <= ws_size) break;
        CB >>= 1;
    }
    const size_t M = (size_t)CB * PN;

    float* base = ws + persistf;
    __hip_bfloat16* pA = (__hip_bfloat16*)base;
    __hip_bfloat16* pB = (__hip_bfloat16*)(base + 3145728);
    float* Wtmp3 = base + 6291456;
    __hip_bfloat16* B0    = (__hip_bfloat16*)(base);             // epack ping
    __hip_bfloat16* B1    = (__hip_bfloat16*)(base + M * 1024);  // epack pong / oe target
    __hip_bfloat16* qp    = (__hip_bfloat16*)(base + M * 2048);  // q single per-head; Apack overlays
    __hip_bfloat16* kp    = (__hip_bfloat16*)(base + M * 2560);  // k single per-head
    __hip_bfloat16* vpT   = (__hip_bfloat16*)(base + M * 3072);  // v single transposed
    unsigned short* Spack = (unsigned short*)(base + M * 3584);  // S single; attb overlays
    float* attb           = base + M * 3584;

    // ----- precompute -----
    pst_atomproj<<<dim3(100), 256, 0, stream>>>(atom_fea, comp_W, atomP);
    pst_embW_reduce<<<dim3(PNDIST), 256, 0, stream>>>(emb_W, S0v, S1v);
    pst_embW_const<<<dim3(1), 256, 0, stream>>>(emb_W, comp_b, emb_b, Cv);
    pst_wext<<<dim3(PB * PN / 256), 256, 0, stream>>>(features, wvec);

    const long WS = 1024L * 1024;
    const long WE = 256L * 1024;
    const long SQK = 3072L * 1024;   // WqkvT per-layer stride (single bf16)
    pst_packT_wL<<<dim3(WE / 256, 3), 256, 0, stream>>>(enc_emb_W, WembT, 256, 1024, WE, 1024L * 512);
    // q combined (split-bf16 3-pass GEMM for the f32 combine; result packed single)
    pst_pack_rows<<<dim3(3 * WS / 256), 256, 0, stream>>>(enc_Wq_W, pA, 10);
    pst_packT_wL<<<dim3(WS / 256, 3), 256, 0, stream>>>(enc_inq_W, pB, 1024, 1024, WS, 1024L * 2048);
    launch_gbf<0, 0>(pA, pB, nullptr, Wtmp3, nullptr,
                     1024, 1024, 1024, 1024L * 2048, 1024L * 2048, WS, 3, stream);
    pst_packT_single<<<dim3(WS / 256, 3), 256, 0, stream>>>(Wtmp3, WqkvT, 1024, 1024, WS, SQK);
    pst_bias_comb<<<dim3(4, 3), 256, 0, stream>>>(enc_Wq_b, enc_inq_W, enc_inq_b, bqkv, 0);
    // k combined
    pst_pack_rows<<<dim3(3 * WS / 256), 256, 0, stream>>>(enc_Wk_W, pA, 10);
    pst_packT_wL<<<dim3(WS / 256, 3), 256, 0, stream>>>(enc_ink_W, pB, 1024, 1024, WS, 1024L * 2048);
    launch_gbf<0, 0>(pA, pB, nullptr, Wtmp3, nullptr,
                     1024, 1024, 1024, 1024L * 2048, 1024L * 2048, WS, 3, stream);
    pst_packT_single<<<dim3(WS / 256, 3), 256, 0, stream>>>(Wtmp3, WqkvT + 1024L * 1024, 1024, 1024, WS, SQK);
    pst_bias_comb<<<dim3(4, 3), 256, 0, stream>>>(enc_Wk_b, enc_ink_W, enc_ink_b, bqkv, 1024);
    // v pack (single) + bias
    pst_packT_single<<<dim3(WS / 256, 3), 256, 0, stream>>>(enc_Wv_W, WqkvT + 2048L * 1024, 1024, 1024, WS, SQK);
    pst_vbias<<<dim3(4, 3), 256, 0, stream>>>(enc_Wv_b, bqkv);
    // out pack (layer 2 only, split for VAR 3)
    pst_packT_wL<<<dim3(WE / 256, 1), 256, 0, stream>>>(enc_out_W + 2 * WE, WoutT2, 1024, 256, WE, 256L * 2048);
    // fused Woe (split for VAR 3)
    pst_pack_rows<<<dim3(2 * WE / 256), 256, 0, stream>>>(enc_out_W, pA, 8);
    launch_gbf<0, 0>(pA, WembT + 1024L * 512, nullptr, Wtmp3, nullptr,
                     1024, 1024, 256, 1024L * 512, 1024L * 512, WS, 2, stream);
    pst_packT_wL<<<dim3(WS / 256, 2), 256, 0, stream>>>(Wtmp3, WoeT, 1024, 1024, WS, 1024L * 2048);
    pst_bias_oe<<<dim3(4, 2), 256, 0, stream>>>(enc_out_b, enc_emb_W, enc_emb_b, boe);

    // ----- embedding + pre-pool of x_init (reads xpk before encoder mutates it) -----
    pst_embed16<<<dim3(PB * PN / 16), 256, 0, stream>>>(
        features, atomP, S0v, S1v, Cv, ln_g, ln_b, xpk);
    pst_pool1<<<dim3(8, PB), 256, 0, stream>>>(wvec, xpk, partiali);

    hipFuncSetAttribute((const void*)pst_gemm_qkv256,
                        hipFuncAttributeMaxDynamicSharedMemorySize, 131072);

    // ----- encoder layers, chunked -----
    for (int cb0 = 0; cb0 < PB; cb0 += CB) {
        const int Mi = (int)M;
        __hip_bfloat16* xps = (__hip_bfloat16*)xpk + (size_t)cb0 * PN * 512;
        __hip_bfloat16* eP = B0;
        __hip_bfloat16* qP2 = B1;
        launch_gbf<4, 3>(xps, WembT, enc_emb_b, nullptr, eP,
                         Mi, PDBIG, PDD, 0, 0, 0, 1, stream);
        for (int l = 0; l < PL; ++l) {
            __hip_bfloat16* Apack = qp;   // overlays qp (dead after S-GEMM)
            {
                dim3 grid(3072 / 256, Mi / 256, 1);
                pst_gemm_qkv256<<<grid, dim3(512), 131072, stream>>>(
                    eP, WqkvT + (size_t)l * SQK, bqkv + (size_t)l * 3072,
                    qp, kp, vpT, PDBIG);
            }
            launch_gbf<5, 1>(qp, kp, nullptr, nullptr, (__hip_bfloat16*)Spack,
                             512, 512, 256, 512L * 256, 512L * 256, 512L * 512,
                             CB * 4, stream);
            pst_attnSM<<<dim3(CB * 64), 256, 0, stream>>>(Spack, wvec, Apack, cb0);
            // att = A @ v: single x single, 1-pass (K=512)
            launch_gbf<0, 1>(Apack, vpT, nullptr, attb, nullptr,
                             512, PDBIG, 512, 512L * 512, 1024L * 512, 512L * 1024,
                             CB, stream);
            pst_spln<<<dim3(Mi), 256, 0, stream>>>(
                attb, eP, enc_ln_g + (size_t)l * PDBIG, enc_ln_b + (size_t)l * PDBIG);
            if (l < PL - 1) {
                launch_gbf<4, 3>(eP, WoeT + (size_t)l * 1024 * 2048, boe + (size_t)l * PDBIG,
                                 nullptr, qP2, Mi, PDBIG, PDBIG, 0, 0, 0, 1, stream);
                __hip_bfloat16* t = eP; eP = qP2; qP2 = t;
            } else {
                launch_gbf<4, 3>(eP, WoutT2, enc_out_b + 2 * (size_t)PDD,
                                 nullptr, xps, Mi, PDD, PDBIG, 0, 0, 0, 1, stream);
            }
        }
    }

    // ----- pool -----
    pst_pool1<<<dim3(8, PB), 256, 0, stream>>>(wvec, xpk, partial);
    pst_pool2<<<dim3(PB), 256, 0, stream>>>(partial, partiali, ln_g, ln_b, out_W, out_b,
                                            (float*)d_out);
}

// Round 23
// 3032.573 us; speedup vs baseline: 1.0959x; 1.0632x over previous
//
#include <hip/hip_runtime.h>
#include <hip/hip_bf16.h>

// ---------------- problem constants ----------------
#define PB 64      // batch
#define PN 512     // set size
#define PFEA 102
#define PE 10
#define PDD 256    // d
#define PH 4
#define PDBIG 1024 // D = d*H
#define PL 3
#define PNDIST 100

typedef __attribute__((ext_vector_type(8))) short s8b;   // 8 bf16 (4 VGPRs)
typedef __attribute__((ext_vector_type(4))) float f4;    // 4 fp32 acc

typedef __attribute__((address_space(1))) const void gvoid_t;
typedef __attribute__((address_space(3))) void lvoid_t;
#define GLDS16(g, s) __builtin_amdgcn_global_load_lds((gvoid_t*)(g), (lvoid_t*)(s), 16, 0, 0)

union bfu { __hip_bfloat16 b; unsigned short u; };

__device__ __forceinline__ float b2f(unsigned short u) {
    return __uint_as_float((unsigned int)u << 16);
}
__device__ __forceinline__ unsigned short f2bu(float v) {
    bfu c; c.b = __float2bfloat16(v); return c.u;
}
__device__ __forceinline__ void split_bf16(float v, __hip_bfloat16& hi, __hip_bfloat16& lo) {
    hi = __float2bfloat16(v);
    lo = __float2bfloat16(v - __bfloat162float(hi));
}
__device__ __forceinline__ void split_u(float v, unsigned short& hu, unsigned short& lu) {
    __hip_bfloat16 h, l; split_bf16(v, h, l);
    bfu c; c.b = h; hu = c.u; c.b = l; lu = c.u;
}

// ---------------- reduction helpers ----------------
__device__ __forceinline__ float block_sum1(float v, float* red, int tid) {
    #pragma unroll
    for (int off = 32; off >= 1; off >>= 1) v += __shfl_xor(v, off);
    __syncthreads();
    if ((tid & 63) == 0) red[tid >> 6] = v;
    __syncthreads();
    return red[0] + red[1] + red[2] + red[3];
}

template<int NR, bool MAXOP>
__device__ __forceinline__ void block_redN(float* v, float* red, int tid) {
    #pragma unroll
    for (int off = 32; off >= 1; off >>= 1) {
        #pragma unroll
        for (int r = 0; r < NR; ++r) {
            float o = __shfl_xor(v[r], off);
            v[r] = MAXOP ? fmaxf(v[r], o) : (v[r] + o);
        }
    }
    __syncthreads();
    if ((tid & 63) == 0) {
        #pragma unroll
        for (int r = 0; r < NR; ++r) red[(tid >> 6) * NR + r] = v[r];
    }
    __syncthreads();
    #pragma unroll
    for (int r = 0; r < NR; ++r) {
        float a = red[r], b = red[NR + r], c = red[2 * NR + r], d = red[3 * NR + r];
        v[r] = MAXOP ? fmaxf(fmaxf(a, b), fmaxf(c, d)) : ((a + b) + (c + d));
    }
    __syncthreads();
}

// ---------------- precompute kernels ----------------
__global__ __launch_bounds__(256) void pst_atomproj(
    const float* __restrict__ atom_fea, const float* __restrict__ comp_W,
    float* __restrict__ atomP)
{
    int a = blockIdx.x, tid = threadIdx.x;
    __shared__ float af[92];
    if (tid < 92) af[tid] = atom_fea[a * 92 + tid];
    __syncthreads();
    float s = 0.0f;
    #pragma unroll 4
    for (int k = 0; k < 92; ++k) s = fmaf(af[k], comp_W[k * PDD + tid], s);
    atomP[a * PDD + tid] = s;
}

__global__ __launch_bounds__(256) void pst_embW_reduce(
    const float* __restrict__ emb_W, float* __restrict__ S0, float* __restrict__ S1)
{
    int f = blockIdx.x, tid = threadIdx.x;
    float s0 = 0.0f, s1 = 0.0f;
    #pragma unroll
    for (int t = 0; t < PE; ++t) {
        float w = emb_W[(f * PE + t) * PDD + tid];
        float tf = (float)t / (float)PE;
        s0 += w;
        s1 = fmaf(2.0f * tf, w, s1);
    }
    S0[f * PDD + tid] = s0;
    S1[f * PDD + tid] = s1;
}

__global__ __launch_bounds__(256) void pst_embW_const(
    const float* __restrict__ emb_W, const float* __restrict__ comp_b,
    const float* __restrict__ emb_b, float* __restrict__ Cv)
{
    int tid = threadIdx.x;
    float s = comp_b[tid] + emb_b[tid];
    for (int m = 0; m < PNDIST * PE; ++m) {
        float tf = (float)(m % PE) / (float)PE;
        s = fmaf(tf * tf, emb_W[m * PDD + tid], s);
    }
    Cv[tid] = s;
}

__global__ __launch_bounds__(256) void pst_wext(
    const float* __restrict__ features, float* __restrict__ wvec)
{
    long i = (long)blockIdx.x * 256 + threadIdx.x;
    wvec[i] = features[i * PFEA];
}

// ---------------- embed: 16 rows/block, f-loop unrolled x4 ----------------
__global__ __launch_bounds__(256) void pst_embed16(
    const float* __restrict__ features, const float* __restrict__ atomP,
    const float* __restrict__ S0, const float* __restrict__ S1,
    const float* __restrict__ Cv, const float* __restrict__ ln_g,
    const float* __restrict__ ln_b, unsigned short* __restrict__ xpk)
{
    int r0 = blockIdx.x * 16, tid = threadIdx.x;
    __shared__ float uv[16][PNDIST];
    __shared__ int idxs[16];
    __shared__ float red[64];
    for (int m = tid; m < 16 * PNDIST; m += 256) {
        int r = m / PNDIST, f = m - r * PNDIST;
        uv[r][f] = 1.0f - features[(long)(r0 + r) * PFEA + 1 + f];
    }
    if (tid < 16) idxs[tid] = (int)features[(long)(r0 + tid) * PFEA + PFEA - 1];
    __syncthreads();

    float acc[16];
    float cv = Cv[tid];
    #pragma unroll
    for (int r = 0; r < 16; ++r) acc[r] = cv + atomP[idxs[r] * PDD + tid];
    for (int f = 0; f < PNDIST; f += 4) {
        float s0v[4], s1v[4];
        #pragma unroll
        for (int u = 0; u < 4; ++u) {
            s0v[u] = S0[(f + u) * PDD + tid];
            s1v[u] = S1[(f + u) * PDD + tid];
        }
        #pragma unroll
        for (int u = 0; u < 4; ++u) {
            #pragma unroll
            for (int r = 0; r < 16; ++r) {
                float uu = uv[r][f + u];
                acc[r] = fmaf(uu, fmaf(uu, s0v[u], s1v[u]), acc[r]);
            }
        }
    }
    float mean[16];
    #pragma unroll
    for (int r = 0; r < 16; ++r) mean[r] = acc[r];
    block_redN<16, false>(mean, red, tid);
    float var[16], dv[16];
    #pragma unroll
    for (int r = 0; r < 16; ++r) { mean[r] *= (1.0f / PDD); dv[r] = acc[r] - mean[r]; var[r] = dv[r] * dv[r]; }
    block_redN<16, false>(var, red, tid);
    #pragma unroll
    for (int r = 0; r < 16; ++r) {
        float y = dv[r] * rsqrtf(var[r] * (1.0f / PDD) + 1e-5f) * ln_g[tid] + ln_b[tid];
        long row = (long)(r0 + r);
        unsigned short hu, lu; split_u(y, hu, lu);
        xpk[row * 512 + tid] = hu;
        xpk[row * 512 + 256 + tid] = lu;
    }
}

// ---------------- 128-tile bf16 MFMA GEMM (BK=64, XOR-swizzled LDS) ----------
// VAR 0: split x split, 3-pass. VAR 1: single x single, 1-pass.
// VAR 3: split x split, 2-pass (Ah Bh + Al Bh) — trunk precision.
// MODE 0: C f32. MODE 4: P split row-pack. MODE 5: P single pack.
template<int MODE, int VAR>
__global__ __launch_bounds__(256) void pst_gemm_bf16(
    const __hip_bfloat16* __restrict__ Ap, const __hip_bfloat16* __restrict__ Bp,
    const float* __restrict__ bias, float* __restrict__ C,
    __hip_bfloat16* __restrict__ P,
    int K, int Nw, long strideA, long strideB, long strideC)
{
    const int lda = (VAR == 1) ? K : 2 * K;
    const int ldb = (VAR == 1) ? K : 2 * K;
    int bz = blockIdx.z;
    Ap += (long)bz * strideA; Bp += (long)bz * strideB;
    if (MODE == 0) C += (long)bz * strideC;
    else P += (long)bz * strideC;

    // T1v2: 2D-rectangular XCD swizzle
    int gx = gridDim.x, gy = gridDim.y;
    int lin = blockIdx.y * gx + blockIdx.x;
    int m0, n0;
    if (((gy & 3) == 0) && ((gx & 1) == 0)) {
        int rm = gy >> 2, rn = gx >> 1;
        int xcd = lin & 7, t = lin >> 3;
        int lm = t % rm, ln = t / rm;
        m0 = ((xcd >> 1) * rm + lm) * 128;
        n0 = ((xcd & 1) * rn + ln) * 128;
    } else {
        m0 = blockIdx.y * 128; n0 = blockIdx.x * 128;
    }

    __shared__ __hip_bfloat16 As[128 * 64];
    __shared__ __hip_bfloat16 Bs[128 * 64];

    int tid = threadIdx.x;
    int w = tid >> 6, l = tid & 63;
    int lr = l & 15, kb = l >> 4;
    int wm = (w >> 1) * 64, wn = (w & 1) * 64;
    int srow = tid >> 3;
    int sg = tid & 7;

    f4 acc[4][4] = {};

    const int K3 = (VAR == 0) ? 3 * K : ((VAR == 3) ? 2 * K : K);
    for (int k0 = 0; k0 < K3; k0 += 64) {
        int kA, kB;
        if (VAR == 0) { kA = (k0 < 2 * K) ? k0 : k0 - 2 * K; kB = (k0 < K) ? k0 : k0 - K; }
        else if (VAR == 3) { kA = k0; kB = (k0 < K) ? k0 : k0 - K; }
        else { kA = k0; kB = k0; }
        #pragma unroll
        for (int s = 0; s < 4; ++s) {
            int r = s * 32 + srow;
            int gsrc = sg ^ (r & 7);
            const __hip_bfloat16* ga = Ap + (long)(m0 + r) * lda + kA + gsrc * 8;
            const __hip_bfloat16* gb = Bp + (long)(n0 + r) * ldb + kB + gsrc * 8;
            GLDS16(ga, As + s * 2048 + w * 512);
            GLDS16(gb, Bs + s * 2048 + w * 512);
        }
        __syncthreads();

        #pragma unroll
        for (int kh = 0; kh < 2; ++kh) {
            s8b af[4], bf[4];
            #pragma unroll
            for (int f = 0; f < 4; ++f) {
                int ra = wm + f * 16 + lr;
                int rb = wn + f * 16 + lr;
                int gr = kh * 4 + kb;
                af[f] = *(const s8b*)(As + ra * 64 + ((gr ^ (ra & 7)) * 8));
                bf[f] = *(const s8b*)(Bs + rb * 64 + ((gr ^ (rb & 7)) * 8));
            }
            #pragma unroll
            for (int i = 0; i < 4; ++i)
                #pragma unroll
                for (int j = 0; j < 4; ++j)
                    acc[i][j] = __builtin_amdgcn_mfma_f32_16x16x32_bf16(af[i], bf[j], acc[i][j], 0, 0, 0);
        }
        __syncthreads();
    }

    // C/D layout: col=lane&15, row=(lane>>4)*4+reg [verified m89/m91]
    #pragma unroll
    for (int i = 0; i < 4; ++i) {
        #pragma unroll
        for (int j = 0; j < 4; ++j) {
            int nbase = n0 + wn + j * 16 + lr;
            int mbase = m0 + wm + i * 16 + kb * 4;
            #pragma unroll
            for (int r = 0; r < 4; ++r) {
                int m = mbase + r;
                int n = nbase;
                float val = acc[i][j][r] + (bias ? bias[n] : 0.0f);
                if (MODE == 0) {
                    C[(long)m * Nw + n] = val;
                } else if (MODE == 4) {
                    __hip_bfloat16 hi, lo; split_bf16(val, hi, lo);
                    long b = (long)m * (2 * Nw) + n;
                    P[b] = hi; P[b + Nw] = lo;
                } else { // MODE 5: single pack
                    P[(long)m * Nw + n] = __float2bfloat16(val);
                }
            }
        }
    }
}

// ---------------- 256-tile 8-wave qkv GEMM (BK=64 conflict-free, dbuf 128KB,
// 1 sync/tile; A split pack hi-read lda=2K, B SINGLE pack ldb=K) ----
__global__ __launch_bounds__(512) void pst_gemm_qkv256(
    const __hip_bfloat16* __restrict__ Ap, const __hip_bfloat16* __restrict__ Bp,
    const float* __restrict__ bias,
    __hip_bfloat16* __restrict__ Pq, __hip_bfloat16* __restrict__ Pk,
    __hip_bfloat16* __restrict__ Pv, int K)
{
    extern __shared__ __hip_bfloat16 lds[];
    __hip_bfloat16* Asd = lds;
    __hip_bfloat16* Bsd = lds + 32768;

    const int lda = 2 * K;
    const int ldb = K;

    int gx = gridDim.x, gy = gridDim.y;
    int lin = blockIdx.y * gx + blockIdx.x;
    int m0, n0;
    if (((gy & 3) == 0) && ((gx & 1) == 0)) {
        int rm = gy >> 2, rn = gx >> 1;
        int xcd = lin & 7, t = lin >> 3;
        int lm = t % rm, ln = t / rm;
        m0 = ((xcd >> 1) * rm + lm) * 256;
        n0 = ((xcd & 1) * rn + ln) * 256;
    } else {
        m0 = blockIdx.y * 256; n0 = blockIdx.x * 256;
    }

    int tid = threadIdx.x;
    int w = tid >> 6, l = tid & 63;
    int lr = l & 15, kb = l >> 4;
    int wm = (w >> 2) * 128;
    int wn = (w & 3) * 64;
    int r6 = tid >> 3;
    int g  = tid & 7;

    f4 acc[8][4] = {};

    const int nt = K / 64;

    auto stage = [&](int tIdx, int buf) {
        int k0 = tIdx * 64;
        #pragma unroll
        for (int i = 0; i < 4; ++i) {
            int r = i * 64 + r6;
            int gs = g ^ (r & 7);
            GLDS16(Ap + (long)(m0 + r) * lda + k0 + gs * 8,
                   Asd + buf * 16384 + i * 4096 + w * 512);
            GLDS16(Bp + (long)(n0 + r) * ldb + k0 + gs * 8,
                   Bsd + buf * 16384 + i * 4096 + w * 512);
        }
    };

    stage(0, 0);
    __syncthreads();

    for (int t = 0; t < nt; ++t) {
        int cur = t & 1;
        if (t + 1 < nt) stage(t + 1, cur ^ 1);

        s8b bfr[4][2];
        #pragma unroll
        for (int fc = 0; fc < 4; ++fc) {
            int rb = wn + fc * 16 + lr;
            #pragma unroll
            for (int kh = 0; kh < 2; ++kh)
                bfr[fc][kh] = *(const s8b*)(Bsd + cur * 16384 + rb * 64 +
                                            (((kh * 4 + kb) ^ (rb & 7)) * 8));
        }
        #pragma unroll
        for (int q = 0; q < 4; ++q) {
            s8b afr[2][2];
            #pragma unroll
            for (int d = 0; d < 2; ++d) {
                int ra = wm + (q * 2 + d) * 16 + lr;
                #pragma unroll
                for (int kh = 0; kh < 2; ++kh)
                    afr[d][kh] = *(const s8b*)(Asd + cur * 16384 + ra * 64 +
                                               (((kh * 4 + kb) ^ (ra & 7)) * 8));
            }
            __builtin_amdgcn_s_setprio(1);
            #pragma unroll
            for (int d = 0; d < 2; ++d)
                #pragma unroll
                for (int fc = 0; fc < 4; ++fc)
                    #pragma unroll
                    for (int kh = 0; kh < 2; ++kh)
                        acc[q * 2 + d][fc] = __builtin_amdgcn_mfma_f32_16x16x32_bf16(
                            afr[d][kh], bfr[fc][kh], acc[q * 2 + d][fc], 0, 0, 0);
            __builtin_amdgcn_s_setprio(0);
        }
        __syncthreads();
    }

    // epilogue: q,k single per-head packs; v single transposed pack (8B writes)
    #pragma unroll
    for (int i = 0; i < 8; ++i) {
        #pragma unroll
        for (int j = 0; j < 4; ++j) {
            int nbase = n0 + wn + j * 16 + lr;
            int mbase = m0 + wm + i * 16 + kb * 4;
            if ((nbase >> 10) == 2) {
                int np = nbase & 1023;
                unsigned short hu[4];
                #pragma unroll
                for (int r = 0; r < 4; ++r)
                    hu[r] = f2bu(acc[i][j][r] + bias[nbase]);
                int bb = mbase >> 9, rr0 = mbase & 511;
                unsigned short* pv = (unsigned short*)Pv + ((long)bb * PDBIG + np) * 512;
                *(ushort4*)(pv + rr0) = make_ushort4(hu[0], hu[1], hu[2], hu[3]);
            } else {
                #pragma unroll
                for (int r = 0; r < 4; ++r) {
                    int m = mbase + r;
                    int n = nbase;
                    float val = acc[i][j][r] + bias[n];
                    int bb = m >> 9, rr = m & 511;
                    int reg2 = n >> 10, np = n & 1023;
                    __hip_bfloat16* dst = (reg2 == 0) ? Pq : Pk;
                    int h = np >> 8, kk = np & 255;
                    dst[(((long)bb * 4 + h) * 512 + rr) * 256 + kk] = __float2bfloat16(val);
                }
            }
        }
    }
}

// ---------------- pack helpers ----------------
__global__ __launch_bounds__(256) void pst_pack_rows(
    const float* __restrict__ src, __hip_bfloat16* __restrict__ dst, int kshift)
{
    long i = (long)blockIdx.x * 256 + threadIdx.x;
    int K = 1 << kshift;
    long m = i >> kshift; int k = (int)(i & (K - 1));
    float v = src[i];
    __hip_bfloat16 hi, lo; split_bf16(v, hi, lo);
    long b = (m << (kshift + 1)) + k;
    dst[b] = hi; dst[b + K] = lo;
}

// row-major SINGLE pack: dst[i] = bf16(src[i])
__global__ __launch_bounds__(256) void pst_pack_single(
    const float* __restrict__ src, __hip_bfloat16* __restrict__ dst)
{
    long i = (long)blockIdx.x * 256 + threadIdx.x;
    dst[i] = __float2bfloat16(src[i]);
}

__global__ __launch_bounds__(256) void pst_packT_wL(
    const float* __restrict__ W, __hip_bfloat16* __restrict__ dst,
    int K, int N, long sSrc, long sDst)
{
    int lyr = blockIdx.y;
    long i = (long)blockIdx.x * 256 + threadIdx.x;
    int k = (int)(i / N), n = (int)(i - (long)k * N);
    float v = W[lyr * sSrc + i];
    __hip_bfloat16 hi, lo; split_bf16(v, hi, lo);
    long b = lyr * sDst + (long)n * (2 * K) + k;
    dst[b] = hi; dst[b + K] = lo;
}

// transpose pack, hi-only (single): W [L][K][N] f32 -> dst [L][N][K] bf16
__global__ __launch_bounds__(256) void pst_packT_single(
    const float* __restrict__ W, __hip_bfloat16* __restrict__ dst,
    int K, int N, long sSrc, long sDst)
{
    int lyr = blockIdx.y;
    long i = (long)blockIdx.x * 256 + threadIdx.x;
    int k = (int)(i / N), n = (int)(i - (long)k * N);
    float v = W[lyr * sSrc + i];
    dst[lyr * sDst + (long)n * K + k] = __float2bfloat16(v);
}

// combined qk bias, 4-way k-parallel (R22): out[l*3072+off+n] = b2 + sum_k b1[k]W2[k][n]
__global__ __launch_bounds__(256) void pst_bias_comb(
    const float* __restrict__ b1, const float* __restrict__ W2,
    const float* __restrict__ b2, float* __restrict__ out, int outOff)
{
    int lyr = blockIdx.y;
    int tid = threadIdx.x;
    int nl = tid & 63;                 // local n within 64-chunk
    int kq = tid >> 6;                 // k-quarter (wave id)
    int n = blockIdx.x * 64 + nl;
    const float* b1l = b1 + (size_t)lyr * PDBIG;
    const float* W2l = W2 + (size_t)lyr * PDBIG * PDBIG;
    __shared__ float part[4][64];
    float s = 0.0f;
    for (int k2 = kq * 256; k2 < kq * 256 + 256; ++k2)
        s = fmaf(b1l[k2], W2l[(long)k2 * PDBIG + n], s);
    part[kq][nl] = s;
    __syncthreads();
    if (tid < 64) {
        int nn = blockIdx.x * 64 + tid;
        out[(size_t)lyr * 3072 + outOff + nn] =
            ((part[0][tid] + part[1][tid]) + (part[2][tid] + part[3][tid]))
            + b2[(size_t)lyr * PDBIG + nn];
    }
}

__global__ __launch_bounds__(256) void pst_bias_oe(
    const float* __restrict__ bout, const float* __restrict__ Wemb,
    const float* __restrict__ bemb, float* __restrict__ boe)
{
    int lyr = blockIdx.y;
    int n = blockIdx.x * 256 + threadIdx.x;
    const float* b1 = bout + (size_t)lyr * PDD;
    const float* W  = Wemb + (size_t)(lyr + 1) * PDD * PDBIG;
    float s = bemb[(size_t)(lyr + 1) * PDBIG + n];
    #pragma unroll 4
    for (int k = 0; k < PDD; ++k)
        s = fmaf(b1[k], W[(long)k * PDBIG + n], s);
    boe[(size_t)lyr * PDBIG + n] = s;
}

__global__ __launch_bounds__(256) void pst_vbias(
    const float* __restrict__ src, float* __restrict__ out)
{
    int lyr = blockIdx.y;
    int i = blockIdx.x * 256 + threadIdx.x;
    out[(size_t)lyr * 3072 + 2048 + i] = src[(size_t)lyr * PDBIG + i];
}

// ---------------- attention softmax (no mask; single S/A) ----------
__global__ __launch_bounds__(256) void pst_attnSM(
    const unsigned short* __restrict__ Sp, const float* __restrict__ wvec,
    __hip_bfloat16* __restrict__ Apack, int bGlobBase)
{
    int blk = blockIdx.x;
    int bLoc = blk >> 6;
    int q0 = (blk & 63) << 3;
    int tid = threadIdx.x;
    int w = tid >> 6, lane = tid & 63;
    int r0 = q0 + w * 2;
    int bGlob = bGlobBase + bLoc;

    float wcol[8];
    #pragma unroll
    for (int j = 0; j < 8; ++j)
        wcol[j] = wvec[(long)bGlob * PN + lane + 64 * j];
    const float scale = 0.0625f;
    float pacc[2][8] = {};

    for (int h = 0; h < PH; ++h) {
        const unsigned short* Sh = Sp + (((long)(bLoc * 4 + h)) * 512 + r0) * 512;
        #pragma unroll
        for (int rr = 0; rr < 2; ++rr) {
            float s[8]; float mx = -1e30f;
            #pragma unroll
            for (int j = 0; j < 8; ++j) {
                float a = b2f(Sh[(long)rr * 512 + lane + 64 * j]) * scale;
                s[j] = a; mx = fmaxf(mx, a);
            }
            #pragma unroll
            for (int off = 32; off >= 1; off >>= 1) mx = fmaxf(mx, __shfl_xor(mx, off));
            float sum = 0.0f;
            #pragma unroll
            for (int j = 0; j < 8; ++j) { s[j] = __expf(s[j] - mx); sum += s[j]; }
            #pragma unroll
            for (int off = 32; off >= 1; off >>= 1) sum += __shfl_xor(sum, off);
            float inv = 1.0f / sum;
            #pragma unroll
            for (int j = 0; j < 8; ++j) pacc[rr][j] = fmaf(s[j], inv, pacc[rr][j]);
        }
    }
    #pragma unroll
    for (int rr = 0; rr < 2; ++rr) {
        float asum = 0.0f;
        #pragma unroll
        for (int j = 0; j < 8; ++j) { pacc[rr][j] *= wcol[j]; asum += pacc[rr][j]; }
        #pragma unroll
        for (int off = 32; off >= 1; off >>= 1) asum += __shfl_xor(asum, off);
        float inv = 1.0f / asum;
        long rowb = ((long)bLoc * PN + r0 + rr) * 512;
        #pragma unroll
        for (int j = 0; j < 8; ++j) {
            int c = lane + 64 * j;
            Apack[rowb + c] = __float2bfloat16(pacc[rr][j] * inv);
        }
    }
}

// ---------------- spln (att now SINGLE bf16 pack, R22) ----------------
__global__ __launch_bounds__(256) void pst_spln(
    const unsigned short* __restrict__ att, __hip_bfloat16* __restrict__ ep,
    const float* __restrict__ g, const float* __restrict__ bb)
{
    int r = blockIdx.x, tid = threadIdx.x;
    __shared__ float red[4];
    int i0 = tid * 4;
    unsigned short* epu = (unsigned short*)ep + (long)r * 2048;
    ushort4 h4 = *(const ushort4*)(epu + i0);
    ushort4 l4 = *(const ushort4*)(epu + 1024 + i0);
    ushort4 a4 = *(const ushort4*)(att + (long)r * 1024 + i0);
    float v[4];
    {
        unsigned short av[4] = {a4.x, a4.y, a4.z, a4.w};
        unsigned short hv[4] = {h4.x, h4.y, h4.z, h4.w};
        unsigned short lv[4] = {l4.x, l4.y, l4.z, l4.w};
        #pragma unroll
        for (int j = 0; j < 4; ++j) {
            float a = b2f(av[j]);
            float sp = (a > 20.0f) ? a : log1pf(expf(a));
            v[j] = b2f(hv[j]) + b2f(lv[j]) + sp;
        }
    }
    float s = v[0] + v[1] + v[2] + v[3];
    float mean = block_sum1(s, red, tid) * (1.0f / PDBIG);
    float vs = 0.0f;
    #pragma unroll
    for (int j = 0; j < 4; ++j) { float dv = v[j] - mean; vs += dv * dv; }
    float var = block_sum1(vs, red, tid) * (1.0f / PDBIG);
    float inv = rsqrtf(var + 1e-5f);
    float4 g4 = *(const float4*)(g + i0);
    float4 b4 = *(const float4*)(bb + i0);
    float gv[4] = {g4.x, g4.y, g4.z, g4.w};
    float bv[4] = {b4.x, b4.y, b4.z, b4.w};
    unsigned short ho[4], lo_[4];
    #pragma unroll
    for (int j = 0; j < 4; ++j) {
        float y = (v[j] - mean) * inv * gv[j] + bv[j];
        split_u(y, ho[j], lo_[j]);
    }
    *(ushort4*)(epu + i0)        = make_ushort4(ho[0], ho[1], ho[2], ho[3]);
    *(ushort4*)(epu + 1024 + i0) = make_ushort4(lo_[0], lo_[1], lo_[2], lo_[3]);
}

// ---------------- pool ----------------
__global__ __launch_bounds__(256) void pst_pool1(
    const float* __restrict__ wvec, const unsigned short* __restrict__ pk,
    float* __restrict__ partial)
{
    int p = blockIdx.x, b = blockIdx.y, tid = threadIdx.x;
    float acc = 0.0f;
    for (int n = p * 64; n < p * 64 + 64; ++n) {
        float w = wvec[(long)b * PN + n];
        long row = (long)b * PN + n;
        float xv = b2f(pk[row * 512 + tid]) + b2f(pk[row * 512 + 256 + tid]);
        acc = fmaf(w, xv, acc);
    }
    partial[((long)b * 8 + p) * PDD + tid] = acc;
}

__global__ __launch_bounds__(256) void pst_pool2(
    const float* __restrict__ partial, const float* __restrict__ partiali,
    const float* __restrict__ ln_g, const float* __restrict__ ln_b,
    const float* __restrict__ out_W, const float* __restrict__ out_b,
    float* __restrict__ out)
{
    int b = blockIdx.x, tid = threadIdx.x;
    __shared__ float red[4];
    float acc = 0.0f;
    #pragma unroll
    for (int p = 0; p < 8; ++p)
        acc += partial[((long)b * 8 + p) * PDD + tid] + partiali[((long)b * 8 + p) * PDD + tid];
    float mean = block_sum1(acc, red, tid) * (1.0f / PDD);
    float dv = acc - mean;
    float var = block_sum1(dv * dv, red, tid) * (1.0f / PDD);
    float y = dv * rsqrtf(var + 1e-5f) * ln_g[tid] + ln_b[tid];
    float s = block_sum1(y * out_W[tid], red, tid);
    if (tid == 0) out[b] = s + out_b[0];
}

// ---------------- host ----------------
template<int MODE, int VAR>
static void launch_gbf(const __hip_bfloat16* A, const __hip_bfloat16* B, const float* bias,
                       float* C, __hip_bfloat16* P, int M, int Nw, int K,
                       long sA, long sB, long sC, int batch, hipStream_t st)
{
    dim3 grid(Nw / 128, M / 128, batch);
    pst_gemm_bf16<MODE, VAR><<<grid, dim3(256), 0, st>>>(A, B, bias, C, P, K, Nw, sA, sB, sC);
}

extern "C" void kernel_launch(void* const* d_in, const int* in_sizes, int n_in,
                              void* d_out, int out_size, void* d_ws, size_t ws_size,
                              hipStream_t stream)
{
    const float* features  = (const float*)d_in[0];
    const float* atom_fea  = (const float*)d_in[1];
    const float* comp_W    = (const float*)d_in[2];
    const float* comp_b    = (const float*)d_in[3];
    const float* emb_W     = (const float*)d_in[4];
    const float* emb_b     = (const float*)d_in[5];
    const float* ln_g      = (const float*)d_in[6];
    const float* ln_b      = (const float*)d_in[7];
    const float* enc_emb_W = (const float*)d_in[8];
    const float* enc_emb_b = (const float*)d_in[9];
    const float* enc_Wq_W  = (const float*)d_in[10];
    const float* enc_Wq_b  = (const float*)d_in[11];
    const float* enc_Wk_W  = (const float*)d_in[12];
    const float* enc_Wk_b  = (const float*)d_in[13];
    const float* enc_Wv_W  = (const float*)d_in[14];
    const float* enc_Wv_b  = (const float*)d_in[15];
    const float* enc_inq_W = (const float*)d_in[16];
    const float* enc_inq_b = (const float*)d_in[17];
    const float* enc_ink_W = (const float*)d_in[18];
    const float* enc_ink_b = (const float*)d_in[19];
    const float* enc_ln_g  = (const float*)d_in[20];
    const float* enc_ln_b  = (const float*)d_in[21];
    const float* enc_out_W = (const float*)d_in[22];
    const float* enc_out_b = (const float*)d_in[23];
    const float* out_W     = (const float*)d_in[24];
    const float* out_b     = (const float*)d_in[25];

    // ----- persistent workspace (floats); WqkvT single (hi-only) -----
    float* ws = (float*)d_ws;
    size_t off = 0;
    unsigned short* xpk  = (unsigned short*)(ws + off); off += (size_t)PB * PN * 512 / 2;
    __hip_bfloat16* WembT = (__hip_bfloat16*)(ws + off); off += (size_t)PL * 1024 * 512 / 2;
    __hip_bfloat16* WqkvT = (__hip_bfloat16*)(ws + off); off += (size_t)PL * 3072 * 1024 / 2;  // single
    __hip_bfloat16* WoutT2 = (__hip_bfloat16*)(ws + off); off += (size_t)256 * 2048 / 2;
    __hip_bfloat16* WoeT  = (__hip_bfloat16*)(ws + off); off += (size_t)2 * 1024 * 2048 / 2;
    float* bqkv  = ws + off; off += (size_t)PL * 3072;
    float* boe   = ws + off; off += (size_t)2 * PDBIG;
    float* atomP = ws + off; off += (size_t)100 * PDD;
    float* S0v   = ws + off; off += (size_t)PNDIST * PDD;
    float* S1v   = ws + off; off += (size_t)PNDIST * PDD;
    float* Cv    = ws + off; off += PDD;
    float* partial  = ws + off; off += (size_t)PB * 8 * PDD;
    float* partiali = ws + off; off += (size_t)PB * 8 * PDD;
    float* wvec  = ws + off; off += (size_t)PB * PN;
    size_t persistf = off;

    const size_t PRE_FL = (size_t)3 * 1024 * 1024 / 2 * 2 + (size_t)3 * 1024 * 1024;
    // chunk rows (floats): B0 1024 + B1 1024 + qp 512 (Apack overlays) + kp 512 +
    // vpT 512 + Spack/attb 1024 = 4608
    const size_t ROW_FL = 4608;
    int CB = 64;
    while (CB > 1) {
        size_t M = (size_t)CB * PN;
        size_t region = M * ROW_FL;
        if (region < PRE_FL) region = PRE_FL;
        if ((persistf + region) * sizeof(float) <= ws_size) break;
        CB >>= 1;
    }
    const size_t M = (size_t)CB * PN;

    float* base = ws + persistf;
    __hip_bfloat16* pA = (__hip_bfloat16*)base;                       // 3x1024x1024 bf16 single
    __hip_bfloat16* pB = (__hip_bfloat16*)(base + 1572864);           // 3x1024x1024 bf16 single
    float* Wtmp3 = base + 3145728;                                    // 3x1024x1024 f32
    __hip_bfloat16* B0    = (__hip_bfloat16*)(base);             // epack ping
    __hip_bfloat16* B1    = (__hip_bfloat16*)(base + M * 1024);  // epack pong / oe target
    __hip_bfloat16* qp    = (__hip_bfloat16*)(base + M * 2048);  // q single per-head; Apack overlays
    __hip_bfloat16* kp    = (__hip_bfloat16*)(base + M * 2560);  // k single per-head
    __hip_bfloat16* vpT   = (__hip_bfloat16*)(base + M * 3072);  // v single transposed
    unsigned short* Spack = (unsigned short*)(base + M * 3584);  // S single; attb overlays
    unsigned short* attb  = (unsigned short*)(base + M * 3584);  // att single (overlay)

    // NOTE: chunk region must also hold the precompute scratch (pA/pB/Wtmp3)
    // pA 1.5M fl + pB 1.5M fl + Wtmp3 3M fl = 6M fl < M*ROW_FL for CB>=2.

    // ----- precompute -----
    pst_atomproj<<<dim3(100), 256, 0, stream>>>(atom_fea, comp_W, atomP);
    pst_embW_reduce<<<dim3(PNDIST), 256, 0, stream>>>(emb_W, S0v, S1v);
    pst_embW_const<<<dim3(1), 256, 0, stream>>>(emb_W, comp_b, emb_b, Cv);
    pst_wext<<<dim3(PB * PN / 256), 256, 0, stream>>>(features, wvec);

    const long WS = 1024L * 1024;
    const long WE = 256L * 1024;
    const long SQK = 3072L * 1024;   // WqkvT per-layer stride (single bf16)
    pst_packT_wL<<<dim3(WE / 256, 3), 256, 0, stream>>>(enc_emb_W, WembT, 256, 1024, WE, 1024L * 512);
    // q combined: single x single 1-pass (result rounded to single pack anyway)
    pst_pack_single<<<dim3(3 * WS / 256), 256, 0, stream>>>(enc_Wq_W, pA);
    pst_packT_single<<<dim3(WS / 256, 3), 256, 0, stream>>>(enc_inq_W, pB, 1024, 1024, WS, WS);
    launch_gbf<0, 1>(pA, pB, nullptr, Wtmp3, nullptr,
                     1024, 1024, 1024, WS, WS, WS, 3, stream);
    pst_packT_single<<<dim3(WS / 256, 3), 256, 0, stream>>>(Wtmp3, WqkvT, 1024, 1024, WS, SQK);
    pst_bias_comb<<<dim3(16, 3), 256, 0, stream>>>(enc_Wq_b, enc_inq_W, enc_inq_b, bqkv, 0);
    // k combined
    pst_pack_single<<<dim3(3 * WS / 256), 256, 0, stream>>>(enc_Wk_W, pA);
    pst_packT_single<<<dim3(WS / 256, 3), 256, 0, stream>>>(enc_ink_W, pB, 1024, 1024, WS, WS);
    launch_gbf<0, 1>(pA, pB, nullptr, Wtmp3, nullptr,
                     1024, 1024, 1024, WS, WS, WS, 3, stream);
    pst_packT_single<<<dim3(WS / 256, 3), 256, 0, stream>>>(Wtmp3, WqkvT + 1024L * 1024, 1024, 1024, WS, SQK);
    pst_bias_comb<<<dim3(16, 3), 256, 0, stream>>>(enc_Wk_b, enc_ink_W, enc_ink_b, bqkv, 1024);
    // v pack (single) + bias
    pst_packT_single<<<dim3(WS / 256, 3), 256, 0, stream>>>(enc_Wv_W, WqkvT + 2048L * 1024, 1024, 1024, WS, SQK);
    pst_vbias<<<dim3(4, 3), 256, 0, stream>>>(enc_Wv_b, bqkv);
    // out pack (layer 2 only, split for VAR 3)
    pst_packT_wL<<<dim3(WE / 256, 1), 256, 0, stream>>>(enc_out_W + 2 * WE, WoutT2, 1024, 256, WE, 256L * 2048);
    // fused Woe = Wout @ Wemb' : 2-pass VAR 3 (A split rows pack, B = WembT split)
    pst_pack_rows<<<dim3(2 * WE / 256), 256, 0, stream>>>(enc_out_W, pA, 8);
    launch_gbf<0, 3>(pA, WembT + 1024L * 512, nullptr, Wtmp3, nullptr,
                     1024, 1024, 256, 1024L * 512, 1024L * 512, WS, 2, stream);
    pst_packT_wL<<<dim3(WS / 256, 2), 256, 0, stream>>>(Wtmp3, WoeT, 1024, 1024, WS, 1024L * 2048);
    pst_bias_oe<<<dim3(4, 2), 256, 0, stream>>>(enc_out_b, enc_emb_W, enc_emb_b, boe);

    // ----- embedding + pre-pool of x_init (reads xpk before encoder mutates it) -----
    pst_embed16<<<dim3(PB * PN / 16), 256, 0, stream>>>(
        features, atomP, S0v, S1v, Cv, ln_g, ln_b, xpk);
    pst_pool1<<<dim3(8, PB), 256, 0, stream>>>(wvec, xpk, partiali);

    hipFuncSetAttribute((const void*)pst_gemm_qkv256,
                        hipFuncAttributeMaxDynamicSharedMemorySize, 131072);

    // ----- encoder layers, chunked -----
    for (int cb0 = 0; cb0 < PB; cb0 += CB) {
        const int Mi = (int)M;
        __hip_bfloat16* xps = (__hip_bfloat16*)xpk + (size_t)cb0 * PN * 512;
        __hip_bfloat16* eP = B0;
        __hip_bfloat16* qP2 = B1;
        launch_gbf<4, 3>(xps, WembT, enc_emb_b, nullptr, eP,
                         Mi, PDBIG, PDD, 0, 0, 0, 1, stream);
        for (int l = 0; l < PL; ++l) {
            __hip_bfloat16* Apack = qp;   // overlays qp (dead after S-GEMM)
            {
                dim3 grid(3072 / 256, Mi / 256, 1);
                pst_gemm_qkv256<<<grid, dim3(512), 131072, stream>>>(
                    eP, WqkvT + (size_t)l * SQK, bqkv + (size_t)l * 3072,
                    qp, kp, vpT, PDBIG);
            }
            launch_gbf<5, 1>(qp, kp, nullptr, nullptr, (__hip_bfloat16*)Spack,
                             512, 512, 256, 512L * 256, 512L * 256, 512L * 512,
                             CB * 4, stream);
            pst_attnSM<<<dim3(CB * 64), 256, 0, stream>>>(Spack, wvec, Apack, cb0);
            // att = A @ v: single x single, 1-pass, SINGLE bf16 out -> attb (overlays Spack)
            launch_gbf<5, 1>(Apack, vpT, nullptr, nullptr, (__hip_bfloat16*)attb,
                             512, PDBIG, 512, 512L * 512, 1024L * 512, 512L * 1024,
                             CB, stream);
            pst_spln<<<dim3(Mi), 256, 0, stream>>>(
                attb, eP, enc_ln_g + (size_t)l * PDBIG, enc_ln_b + (size_t)l * PDBIG);
            if (l < PL - 1) {
                launch_gbf<4, 3>(eP, WoeT + (size_t)l * 1024 * 2048, boe + (size_t)l * PDBIG,
                                 nullptr, qP2, Mi, PDBIG, PDBIG, 0, 0, 0, 1, stream);
                __hip_bfloat16* t = eP; eP = qP2; qP2 = t;
            } else {
                launch_gbf<4, 3>(eP, WoutT2, enc_out_b + 2 * (size_t)PDD,
                                 nullptr, xps, Mi, PDD, PDBIG, 0, 0, 0, 1, stream);
            }
        }
    }

    // ----- pool -----
    pst_pool1<<<dim3(8, PB), 256, 0, stream>>>(wvec, xpk, partial);
    pst_pool2<<<dim3(PB), 256, 0, stream>>>(partial, partiali, ln_g, ln_b, out_W, out_b,
                                            (float*)d_out);
}